// Round 15
// baseline (354.322 us; speedup 1.0000x reference)
//
#include <hip/hip_runtime.h>
#include <hip/hip_fp16.h>

#define NN 50000
#define EE 800000
#define DD 128
#define CC 16
#define HCOPIES 64
#define NRANGE 16384   // nodes per LDS-hist range (64KB LDS)

typedef __attribute__((ext_vector_type(8))) short bf16x8;
typedef __attribute__((ext_vector_type(4))) float f32x4;

__device__ inline unsigned short f2bf(float x) {
    unsigned int u = __float_as_uint(x);
    unsigned int r = (u + 0x7FFFu + ((u >> 16) & 1u)) >> 16;
    return (unsigned short)r;
}
__device__ inline float bf2f(unsigned short h) {
    return __uint_as_float(((unsigned int)h) << 16);
}

// ---------------- LDS-privatized degree histogram (packed: src lo16, dst hi16) ----------------
__global__ __launch_bounds__(256) void k_hist_lds(
        const int* __restrict__ src, const int* __restrict__ dst,
        unsigned int* __restrict__ hist) {
    __shared__ unsigned int lds[NRANGE];
    const int t = threadIdx.x;
    const int r = blockIdx.x / HCOPIES;
    const int sub = blockIdx.x % HCOPIES;
    const int base = r * NRANGE;
    const int hi = min(base + NRANGE, NN) - base;   // range size (<= NRANGE)

    for (int i = t; i < NRANGE; i += 256) lds[i] = 0;
    __syncthreads();

    const int chunk = EE / HCOPIES;                 // 12500
    const int e0 = sub * chunk;
    const int e1 = e0 + chunk;
    for (int e = e0 + t; e < e1; e += 256) {
        int s = src[e];
        int d = dst[e];
        unsigned us = (unsigned)(s - base);
        unsigned ud = (unsigned)(d - base);
        if (us < (unsigned)hi) atomicAdd(&lds[us], 1u);
        if (ud < (unsigned)hi) atomicAdd(&lds[ud], 0x10000u);
    }
    __syncthreads();

    for (int i = t; i < hi; i += 256) hist[(size_t)sub * NN + base + i] = lds[i];
}

__global__ void k_reduce_deg(const unsigned int* __restrict__ hist,
                             int* __restrict__ cd,
                             float* __restrict__ iso, float* __restrict__ isi) {
    int i = blockIdx.x * blockDim.x + threadIdx.x;
    if (i < NN) {
        unsigned int sum = 0;
#pragma unroll
        for (int c = 0; c < HCOPIES; ++c) sum += hist[(size_t)c * NN + i];
        unsigned int csv = sum & 0xFFFFu;
        unsigned int cdv = sum >> 16;
        cd[i] = (int)cdv;
        iso[i] = rsqrtf(fmaxf((float)csv, 1.0f));
        isi[i] = rsqrtf(fmaxf((float)cdv, 1.0f));
    }
}

// ---------------- hierarchical exclusive scan: cd -> rowptr ----------------
#define SBLK 256
#define NBLK_SCAN ((NN + SBLK - 1) / SBLK)   // 196

__global__ __launch_bounds__(SBLK) void k_blocksum(const int* __restrict__ cnt,
                                                   int* __restrict__ partial) {
    __shared__ int s[SBLK];
    int t = threadIdx.x;
    int i = blockIdx.x * SBLK + t;
    int v = (i < NN) ? cnt[i] : 0;
    s[t] = v;
    __syncthreads();
    for (int off = SBLK / 2; off > 0; off >>= 1) {
        if (t < off) s[t] += s[t + off];
        __syncthreads();
    }
    if (t == 0) partial[blockIdx.x] = s[0];
}

__global__ __launch_bounds__(SBLK) void k_scanpartial(const int* __restrict__ partial,
                                                      int* __restrict__ pp,
                                                      int* __restrict__ rowptr) {
    __shared__ int s[SBLK];
    int t = threadIdx.x;
    int v = (t < NBLK_SCAN) ? partial[t] : 0;
    s[t] = v;
    __syncthreads();
    for (int off = 1; off < SBLK; off <<= 1) {
        int x = (t >= off) ? s[t - off] : 0;
        __syncthreads();
        s[t] += x;
        __syncthreads();
    }
    if (t < NBLK_SCAN) pp[t] = s[t] - v;   // exclusive prefix of block partials
    if (t == SBLK - 1) rowptr[NN] = s[t];  // grand total (== EE)
}

__global__ __launch_bounds__(SBLK) void k_writerowptr(const int* __restrict__ cnt,
                                                      const int* __restrict__ pp,
                                                      int* __restrict__ rowptr) {
    __shared__ int s[SBLK];
    int t = threadIdx.x;
    int i = blockIdx.x * SBLK + t;
    int v = (i < NN) ? cnt[i] : 0;
    s[t] = v;
    __syncthreads();
    for (int off = 1; off < SBLK; off <<= 1) {
        int x = (t >= off) ? s[t - off] : 0;
        __syncthreads();
        s[t] += x;
        __syncthreads();
    }
    if (i < NN) rowptr[i] = pp[blockIdx.x] + s[t] - v;
}

// ---------------- CSR fill, packed 4B: (src:16 | fp16 weight:16), nt store ----------------
__global__ void k_fill(const int* __restrict__ src, const int* __restrict__ dst,
                       const float* __restrict__ ew, const float* __restrict__ iso,
                       const float* __restrict__ isi, const int* __restrict__ rowptr,
                       int* __restrict__ cursor, unsigned int* __restrict__ pairs) {
    int e = blockIdx.x * blockDim.x + threadIdx.x;
    if (e < EE) {
        int d = dst[e];
        int s = src[e];
        int pos = atomicAdd(&cursor[d], 1);
        float w = ew[e] * iso[s] * isi[d];
        unsigned short hw = __half_as_ushort(__float2half(w));
        unsigned int pk = ((unsigned)s & 0xFFFFu) | ((unsigned)hw << 16);
        int idx = rowptr[d] + pos;
        if ((unsigned)idx < EE)
            __builtin_nontemporal_store(pk, &pairs[idx]);   // bypass L2 line-allocate
    }
}

// ---------------- inputs fp32 -> bf16 (for layer-0 gather + res GEMM) ----------------
__global__ __launch_bounds__(256) void k_tobf(const float* __restrict__ X,
                                              unsigned short* __restrict__ Hb) {
    int i = blockIdx.x * blockDim.x + threadIdx.x;   // NN*DD/4 threads
    if (i < NN * DD / 4) {
        float4 v = *(const float4*)&X[i * 4];
        ushort4 h;
        h.x = f2bf(v.x); h.y = f2bf(v.y); h.z = f2bf(v.z); h.w = f2bf(v.w);
        *(ushort4*)&Hb[i * 4] = h;
    }
}

// ---------------- CSR gather: 2 nodes/wave (half-wave x ushort4), 8-deep, nt streams ----------------
__global__ __launch_bounds__(256) void k_gather_bf(
        const unsigned short* __restrict__ H, const int* __restrict__ rowptr,
        const unsigned int* __restrict__ pairs, unsigned short* __restrict__ G) {
    const int t = threadIdx.x;
    const int lane = t & 63;
    const int half = lane >> 5;
    const int l32 = lane & 31;
    const int node = blockIdx.x * 8 + (t >> 6) * 2 + half;
    if (node >= NN) return;
    const int cofs = l32 * 4;                       // ushort4 col offset
    int j = rowptr[node];
    int end = rowptr[node + 1];
    j = max(0, min(j, EE));
    end = max(j, min(end, EE));

    float4 a0 = make_float4(0.f, 0.f, 0.f, 0.f);
    float4 a1 = make_float4(0.f, 0.f, 0.f, 0.f);
    float4 a2 = make_float4(0.f, 0.f, 0.f, 0.f);
    float4 a3 = make_float4(0.f, 0.f, 0.f, 0.f);

    for (; j + 7 < end; j += 8) {
        unsigned p0 = __builtin_nontemporal_load(&pairs[j + 0]);
        unsigned p1 = __builtin_nontemporal_load(&pairs[j + 1]);
        unsigned p2 = __builtin_nontemporal_load(&pairs[j + 2]);
        unsigned p3 = __builtin_nontemporal_load(&pairs[j + 3]);
        unsigned p4 = __builtin_nontemporal_load(&pairs[j + 4]);
        unsigned p5 = __builtin_nontemporal_load(&pairs[j + 5]);
        unsigned p6 = __builtin_nontemporal_load(&pairs[j + 6]);
        unsigned p7 = __builtin_nontemporal_load(&pairs[j + 7]);
        int c0 = (p0 & 0xFFFFu) < NN ? (int)(p0 & 0xFFFFu) : 0;
        int c1 = (p1 & 0xFFFFu) < NN ? (int)(p1 & 0xFFFFu) : 0;
        int c2 = (p2 & 0xFFFFu) < NN ? (int)(p2 & 0xFFFFu) : 0;
        int c3 = (p3 & 0xFFFFu) < NN ? (int)(p3 & 0xFFFFu) : 0;
        int c4 = (p4 & 0xFFFFu) < NN ? (int)(p4 & 0xFFFFu) : 0;
        int c5 = (p5 & 0xFFFFu) < NN ? (int)(p5 & 0xFFFFu) : 0;
        int c6 = (p6 & 0xFFFFu) < NN ? (int)(p6 & 0xFFFFu) : 0;
        int c7 = (p7 & 0xFFFFu) < NN ? (int)(p7 & 0xFFFFu) : 0;
        ushort4 h0 = *(const ushort4*)&H[c0 * DD + cofs];
        ushort4 h1 = *(const ushort4*)&H[c1 * DD + cofs];
        ushort4 h2 = *(const ushort4*)&H[c2 * DD + cofs];
        ushort4 h3 = *(const ushort4*)&H[c3 * DD + cofs];
        ushort4 h4 = *(const ushort4*)&H[c4 * DD + cofs];
        ushort4 h5 = *(const ushort4*)&H[c5 * DD + cofs];
        ushort4 h6 = *(const ushort4*)&H[c6 * DD + cofs];
        ushort4 h7 = *(const ushort4*)&H[c7 * DD + cofs];
        float w0 = __half2float(__ushort_as_half((unsigned short)(p0 >> 16)));
        float w1 = __half2float(__ushort_as_half((unsigned short)(p1 >> 16)));
        float w2 = __half2float(__ushort_as_half((unsigned short)(p2 >> 16)));
        float w3 = __half2float(__ushort_as_half((unsigned short)(p3 >> 16)));
        float w4 = __half2float(__ushort_as_half((unsigned short)(p4 >> 16)));
        float w5 = __half2float(__ushort_as_half((unsigned short)(p5 >> 16)));
        float w6 = __half2float(__ushort_as_half((unsigned short)(p6 >> 16)));
        float w7 = __half2float(__ushort_as_half((unsigned short)(p7 >> 16)));
        a0.x = fmaf(bf2f(h0.x), w0, a0.x); a0.y = fmaf(bf2f(h0.y), w0, a0.y);
        a0.z = fmaf(bf2f(h0.z), w0, a0.z); a0.w = fmaf(bf2f(h0.w), w0, a0.w);
        a1.x = fmaf(bf2f(h1.x), w1, a1.x); a1.y = fmaf(bf2f(h1.y), w1, a1.y);
        a1.z = fmaf(bf2f(h1.z), w1, a1.z); a1.w = fmaf(bf2f(h1.w), w1, a1.w);
        a2.x = fmaf(bf2f(h2.x), w2, a2.x); a2.y = fmaf(bf2f(h2.y), w2, a2.y);
        a2.z = fmaf(bf2f(h2.z), w2, a2.z); a2.w = fmaf(bf2f(h2.w), w2, a2.w);
        a3.x = fmaf(bf2f(h3.x), w3, a3.x); a3.y = fmaf(bf2f(h3.y), w3, a3.y);
        a3.z = fmaf(bf2f(h3.z), w3, a3.z); a3.w = fmaf(bf2f(h3.w), w3, a3.w);
        a0.x = fmaf(bf2f(h4.x), w4, a0.x); a0.y = fmaf(bf2f(h4.y), w4, a0.y);
        a0.z = fmaf(bf2f(h4.z), w4, a0.z); a0.w = fmaf(bf2f(h4.w), w4, a0.w);
        a1.x = fmaf(bf2f(h5.x), w5, a1.x); a1.y = fmaf(bf2f(h5.y), w5, a1.y);
        a1.z = fmaf(bf2f(h5.z), w5, a1.z); a1.w = fmaf(bf2f(h5.w), w5, a1.w);
        a2.x = fmaf(bf2f(h6.x), w6, a2.x); a2.y = fmaf(bf2f(h6.y), w6, a2.y);
        a2.z = fmaf(bf2f(h6.z), w6, a2.z); a2.w = fmaf(bf2f(h6.w), w6, a2.w);
        a3.x = fmaf(bf2f(h7.x), w7, a3.x); a3.y = fmaf(bf2f(h7.y), w7, a3.y);
        a3.z = fmaf(bf2f(h7.z), w7, a3.z); a3.w = fmaf(bf2f(h7.w), w7, a3.w);
    }
    for (; j < end; ++j) {
        unsigned p0 = __builtin_nontemporal_load(&pairs[j]);
        int c0 = (p0 & 0xFFFFu) < NN ? (int)(p0 & 0xFFFFu) : 0;
        float w0 = __half2float(__ushort_as_half((unsigned short)(p0 >> 16)));
        ushort4 h0 = *(const ushort4*)&H[c0 * DD + cofs];
        a0.x = fmaf(bf2f(h0.x), w0, a0.x); a0.y = fmaf(bf2f(h0.y), w0, a0.y);
        a0.z = fmaf(bf2f(h0.z), w0, a0.z); a0.w = fmaf(bf2f(h0.w), w0, a0.w);
    }
    float ox = (a0.x + a1.x) + (a2.x + a3.x);
    float oy = (a0.y + a1.y) + (a2.y + a3.y);
    float oz = (a0.z + a1.z) + (a2.z + a3.z);
    float ow = (a0.w + a1.w) + (a2.w + a3.w);
    unsigned long long pk =
        (unsigned long long)f2bf(ox) |
        ((unsigned long long)f2bf(oy) << 16) |
        ((unsigned long long)f2bf(oz) << 32) |
        ((unsigned long long)f2bf(ow) << 48);
    __builtin_nontemporal_store(pk, (unsigned long long*)&G[node * DD + cofs]);
}

// ---------------- W prep: fp32 [k][c] -> bf16 hi/lo, transposed layout [c][k] ----------------
__global__ __launch_bounds__(128) void k_prepw(
        const float* __restrict__ W1, const float* __restrict__ W2,
        const float* __restrict__ W3, const float* __restrict__ W4,
        const float* __restrict__ Wr,
        unsigned short* __restrict__ WH, unsigned short* __restrict__ WL) {
    int m = blockIdx.x >> 7;
    int c = blockIdx.x & 127;
    int k = threadIdx.x;
    const float* Wm = (m == 0) ? W1 : (m == 1) ? W2 : (m == 2) ? W3 : (m == 3) ? W4 : Wr;
    float x = Wm[k * 128 + c];
    unsigned short hi = f2bf(x);
    unsigned short lo = f2bf(x - bf2f(hi));
    int off = m * 16384 + c * 128 + k;
    WH[off] = hi;
    WL[off] = lo;
}

// ---------------- MFMA GEMM, bf16 input: W in registers, X-only LDS (16KB) ----------------
#define GTILE 64
__global__ __launch_bounds__(512) void k_gemm_mfma(
        const unsigned short* __restrict__ Xb,
        const unsigned short* __restrict__ Wh, const unsigned short* __restrict__ Wl,
        const float* __restrict__ bias, const float* __restrict__ RES,
        float* __restrict__ Yf, unsigned short* __restrict__ Yb, int M, int relu) {
    __shared__ unsigned short Xs[GTILE * 128];

    const int t = threadIdx.x;
    const int row0 = blockIdx.x * GTILE;

    const int lane = t & 63;
    const int wav = t >> 6;
    const int lr = lane & 15;
    const int lk = lane >> 4;

    bf16x8 bh[4], bl[4];
    {
        const int c = 16 * wav + lr;
#pragma unroll
        for (int k0 = 0; k0 < 4; ++k0) {
            int off = c * 128 + k0 * 32 + lk * 8;
            bh[k0] = *(const bf16x8*)&Wh[off];
            bl[k0] = *(const bf16x8*)&Wl[off];
        }
    }

    for (int i = t; i < GTILE * 16; i += 512) {
        int r = i >> 4;
        int c8 = i & 15;
        int gr = row0 + r;
        bf16x8 v = {0, 0, 0, 0, 0, 0, 0, 0};
        if (gr < M) v = *(const bf16x8*)&Xb[(size_t)gr * 128 + c8 * 8];
        int slot = (c8 * 8) ^ ((r & 7) << 3);
        *(bf16x8*)&Xs[r * 128 + slot] = v;
    }
    __syncthreads();

    f32x4 acc[4];
#pragma unroll
    for (int m = 0; m < 4; ++m) acc[m] = (f32x4){0.f, 0.f, 0.f, 0.f};

#pragma unroll
    for (int k0 = 0; k0 < 4; ++k0) {
        const int kbase = k0 * 32 + lk * 8;
        bf16x8 ah[4];
#pragma unroll
        for (int m = 0; m < 4; ++m) {
            int row = 16 * m + lr;
            ah[m] = *(const bf16x8*)&Xs[row * 128 + (kbase ^ ((row & 7) << 3))];
        }
#pragma unroll
        for (int m = 0; m < 4; ++m) {
            acc[m] = __builtin_amdgcn_mfma_f32_16x16x32_bf16(ah[m], bh[k0], acc[m], 0, 0, 0);
            acc[m] = __builtin_amdgcn_mfma_f32_16x16x32_bf16(ah[m], bl[k0], acc[m], 0, 0, 0);
        }
    }

    {
        int gc = 16 * wav + lr;
        float bv = bias[gc];
#pragma unroll
        for (int m = 0; m < 4; ++m) {
#pragma unroll
            for (int j = 0; j < 4; ++j) {
                int gr = row0 + 16 * m + lk * 4 + j;
                if (gr < M) {
                    float a = acc[m][j] + bv;
                    if (RES) a += RES[(long long)gr * DD + gc];
                    if (relu) a = fmaxf(a, 0.f);
                    if (Yb) Yb[(long long)gr * DD + gc] = f2bf(a);
                    else    Yf[(long long)gr * DD + gc] = a;
                }
            }
        }
    }
}

// ---------------- final projection: out[M,16] = X[M,128] @ Wo[128,16] + bo ----------------
__global__ __launch_bounds__(256) void k_gemm_out(
        const float* __restrict__ X, const float* __restrict__ Wo,
        const float* __restrict__ bo, float* __restrict__ Y, int M) {
    __shared__ float Wlds[128 * 16];
    int t = threadIdx.x;
    for (int i = t * 4; i < 128 * 16; i += 256 * 4) {
        *(float4*)&Wlds[i] = *(const float4*)&Wo[i];
    }
    __syncthreads();
    int r = blockIdx.x * blockDim.x + t;
    if (r < M) {
        float acc[16];
#pragma unroll
        for (int j = 0; j < 16; ++j) acc[j] = bo[j];
#pragma unroll
        for (int k = 0; k < 128; k += 4) {
            float4 x = *(const float4*)&X[(long long)r * DD + k];
#pragma unroll
            for (int j = 0; j < 16; ++j) {
                acc[j] += x.x * Wlds[(k + 0) * 16 + j] + x.y * Wlds[(k + 1) * 16 + j]
                        + x.z * Wlds[(k + 2) * 16 + j] + x.w * Wlds[(k + 3) * 16 + j];
            }
        }
#pragma unroll
        for (int j = 0; j < 16; j += 4) {
            float4 o = make_float4(acc[j], acc[j + 1], acc[j + 2], acc[j + 3]);
            *(float4*)&Y[(long long)r * CC + j] = o;
        }
    }
}

extern "C" void kernel_launch(void* const* d_in, const int* in_sizes, int n_in,
                              void* d_out, int out_size, void* d_ws, size_t ws_size,
                              hipStream_t stream) {
    const int*   src = (const int*)d_in[0];
    const int*   dst = (const int*)d_in[1];
    const float* inputs = (const float*)d_in[2];
    const float* ew  = (const float*)d_in[3];
    const float* W1  = (const float*)d_in[4];
    const float* b1  = (const float*)d_in[5];
    const float* W2  = (const float*)d_in[6];
    const float* b2  = (const float*)d_in[7];
    const float* W3  = (const float*)d_in[8];
    const float* b3  = (const float*)d_in[9];
    const float* W4  = (const float*)d_in[10];
    const float* b4  = (const float*)d_in[11];
    const float* Wr  = (const float*)d_in[12];
    const float* br  = (const float*)d_in[13];
    const float* Wo  = (const float*)d_in[14];
    const float* bo  = (const float*)d_in[15];
    float* out = (float*)d_out;

    // workspace layout
    char* p = (char*)d_ws;
    float* iso    = (float*)p; p += sizeof(float) * NN;
    float* isi    = (float*)p; p += sizeof(float) * NN;
    int*   cs     = (int*)p;   p += sizeof(int) * NN;      // reused as WHg
    int*   cd     = (int*)p;   p += sizeof(int) * NN;
    int*   cursor = (int*)p;   p += sizeof(int) * NN;
    int*   rowptr = (int*)p;   p += sizeof(int) * (NN + 1);
    int*   partial= (int*)p;   p += sizeof(int) * NBLK_SCAN;
    int*   pp     = (int*)p;   p += sizeof(int) * NBLK_SCAN;
    p = (char*)(((uintptr_t)p + 255) & ~(uintptr_t)255);
    unsigned int* pairs = (unsigned int*)p; p += sizeof(unsigned int) * EE;
    p = (char*)(((uintptr_t)p + 255) & ~(uintptr_t)255);
    float* RES    = (float*)p; p += sizeof(float) * (size_t)NN * DD;
    float* G      = (float*)p; p += sizeof(float) * (size_t)NN * DD;
    float* X0     = (float*)p; p += sizeof(float) * (size_t)NN * DD;

    // aliases:
    unsigned short* WHg = (unsigned short*)cs;            // 160KB (cs + part of cd)
    unsigned short* WLg = WHg + 5 * 16384;                // 160KB
    unsigned int*   hist = (unsigned int*)G;              // 64 copies x 50K = 12.8MB, pre-layers
    unsigned short* Gb  = (unsigned short*)G;             // bf16 gather output (12.8MB)
    unsigned short* H   = (unsigned short*)X0;            // bf16 intermediate (lower half of X0)
    unsigned short* Hin = H + (size_t)NN * DD;            // bf16 inputs (upper half of X0)

    const int GEMM_GRID = (NN + GTILE - 1) / GTILE;       // 782
    const int NRANGES = (NN + NRANGE - 1) / NRANGE;       // 4

    // ---- degrees via LDS-privatized histogram ----
    hipMemsetAsync(cursor, 0, sizeof(int) * NN, stream);
    k_hist_lds<<<NRANGES * HCOPIES, 256, 0, stream>>>(src, dst, hist);
    k_reduce_deg<<<(NN + 255) / 256, 256, 0, stream>>>(hist, cd, iso, isi);
    k_blocksum<<<NBLK_SCAN, SBLK, 0, stream>>>(cd, partial);
    k_scanpartial<<<1, SBLK, 0, stream>>>(partial, pp, rowptr);
    k_writerowptr<<<NBLK_SCAN, SBLK, 0, stream>>>(cd, pp, rowptr);
    k_fill<<<(EE + 255) / 256, 256, 0, stream>>>(src, dst, ew, iso, isi, rowptr, cursor, pairs);

    // ---- prep bf16 weights + bf16 inputs ----
    k_prepw<<<5 * 128, 128, 0, stream>>>(W1, W2, W3, W4, Wr, WHg, WLg);
    k_tobf<<<(NN * DD / 4 + 255) / 256, 256, 0, stream>>>(inputs, Hin);

    // ---- res = bf16(inputs) @ Wr + br (fp32 out) ----
    k_gemm_mfma<<<GEMM_GRID, 512, 0, stream>>>(Hin, WHg + 4 * 16384, WLg + 4 * 16384,
                                               br, nullptr, RES, nullptr, NN, 0);

    const float* bs[4] = {b1, b2, b3, b4};
    for (int l = 0; l < 4; ++l) {
        const unsigned short* Hs = (l == 0) ? Hin : H;
        k_gather_bf<<<(NN + 7) / 8, 256, 0, stream>>>(Hs, rowptr, pairs, Gb);

        if (l < 3) {
            k_gemm_mfma<<<GEMM_GRID, 512, 0, stream>>>(Gb, WHg + l * 16384, WLg + l * 16384,
                                                       bs[l], nullptr, nullptr, H, NN, 1);
        } else {
            k_gemm_mfma<<<GEMM_GRID, 512, 0, stream>>>(Gb, WHg + l * 16384, WLg + l * 16384,
                                                       bs[l], RES, X0, nullptr, NN, 1);
        }
    }

    k_gemm_out<<<(NN + 255) / 256, 256, 0, stream>>>(X0, Wo, bo, out, NN);
}

// Round 16
// 324.728 us; speedup vs baseline: 1.0911x; 1.0911x over previous
//
#include <hip/hip_runtime.h>
#include <hip/hip_fp16.h>

#define NN 50000
#define EE 800000
#define DD 128
#define CC 16
#define HCOPIES 64
#define NRANGE 16384   // nodes per LDS-hist range (64KB LDS)

typedef __attribute__((ext_vector_type(8))) short bf16x8;
typedef __attribute__((ext_vector_type(4))) float f32x4;

__device__ inline unsigned short f2bf(float x) {
    unsigned int u = __float_as_uint(x);
    unsigned int r = (u + 0x7FFFu + ((u >> 16) & 1u)) >> 16;
    return (unsigned short)r;
}
__device__ inline float bf2f(unsigned short h) {
    return __uint_as_float(((unsigned int)h) << 16);
}

// ---------------- LDS-privatized degree histogram (packed: src lo16, dst hi16) ----------------
__global__ __launch_bounds__(256) void k_hist_lds(
        const int* __restrict__ src, const int* __restrict__ dst,
        unsigned int* __restrict__ hist) {
    __shared__ unsigned int lds[NRANGE];
    const int t = threadIdx.x;
    const int r = blockIdx.x / HCOPIES;
    const int sub = blockIdx.x % HCOPIES;
    const int base = r * NRANGE;
    const int hi = min(base + NRANGE, NN) - base;   // range size (<= NRANGE)

    for (int i = t; i < NRANGE; i += 256) lds[i] = 0;
    __syncthreads();

    const int chunk = EE / HCOPIES;                 // 12500
    const int e0 = sub * chunk;
    const int e1 = e0 + chunk;
    for (int e = e0 + t; e < e1; e += 256) {
        int s = src[e];
        int d = dst[e];
        unsigned us = (unsigned)(s - base);
        unsigned ud = (unsigned)(d - base);
        if (us < (unsigned)hi) atomicAdd(&lds[us], 1u);
        if (ud < (unsigned)hi) atomicAdd(&lds[ud], 0x10000u);
    }
    __syncthreads();

    for (int i = t; i < hi; i += 256) hist[(size_t)sub * NN + base + i] = lds[i];
}

__global__ void k_reduce_deg(const unsigned int* __restrict__ hist,
                             int* __restrict__ cd,
                             float* __restrict__ iso, float* __restrict__ isi) {
    int i = blockIdx.x * blockDim.x + threadIdx.x;
    if (i < NN) {
        unsigned int sum = 0;
#pragma unroll
        for (int c = 0; c < HCOPIES; ++c) sum += hist[(size_t)c * NN + i];
        unsigned int csv = sum & 0xFFFFu;
        unsigned int cdv = sum >> 16;
        cd[i] = (int)cdv;
        iso[i] = rsqrtf(fmaxf((float)csv, 1.0f));
        isi[i] = rsqrtf(fmaxf((float)cdv, 1.0f));
    }
}

// ---------------- hierarchical exclusive scan: cd -> rowptr ----------------
#define SBLK 256
#define NBLK_SCAN ((NN + SBLK - 1) / SBLK)   // 196

__global__ __launch_bounds__(SBLK) void k_blocksum(const int* __restrict__ cnt,
                                                   int* __restrict__ partial) {
    __shared__ int s[SBLK];
    int t = threadIdx.x;
    int i = blockIdx.x * SBLK + t;
    int v = (i < NN) ? cnt[i] : 0;
    s[t] = v;
    __syncthreads();
    for (int off = SBLK / 2; off > 0; off >>= 1) {
        if (t < off) s[t] += s[t + off];
        __syncthreads();
    }
    if (t == 0) partial[blockIdx.x] = s[0];
}

__global__ __launch_bounds__(SBLK) void k_scanpartial(const int* __restrict__ partial,
                                                      int* __restrict__ pp,
                                                      int* __restrict__ rowptr) {
    __shared__ int s[SBLK];
    int t = threadIdx.x;
    int v = (t < NBLK_SCAN) ? partial[t] : 0;
    s[t] = v;
    __syncthreads();
    for (int off = 1; off < SBLK; off <<= 1) {
        int x = (t >= off) ? s[t - off] : 0;
        __syncthreads();
        s[t] += x;
        __syncthreads();
    }
    if (t < NBLK_SCAN) pp[t] = s[t] - v;   // exclusive prefix of block partials
    if (t == SBLK - 1) rowptr[NN] = s[t];  // grand total (== EE)
}

__global__ __launch_bounds__(SBLK) void k_writerowptr(const int* __restrict__ cnt,
                                                      const int* __restrict__ pp,
                                                      int* __restrict__ rowptr) {
    __shared__ int s[SBLK];
    int t = threadIdx.x;
    int i = blockIdx.x * SBLK + t;
    int v = (i < NN) ? cnt[i] : 0;
    s[t] = v;
    __syncthreads();
    for (int off = 1; off < SBLK; off <<= 1) {
        int x = (t >= off) ? s[t - off] : 0;
        __syncthreads();
        s[t] += x;
        __syncthreads();
    }
    if (i < NN) rowptr[i] = pp[blockIdx.x] + s[t] - v;
}

// ---------------- CSR fill, packed 4B: (src:16 | fp16 weight:16) ----------------
__global__ void k_fill(const int* __restrict__ src, const int* __restrict__ dst,
                       const float* __restrict__ ew, const float* __restrict__ iso,
                       const float* __restrict__ isi, const int* __restrict__ rowptr,
                       int* __restrict__ cursor, unsigned int* __restrict__ pairs) {
    int e = blockIdx.x * blockDim.x + threadIdx.x;
    if (e < EE) {
        int d = dst[e];
        int s = src[e];
        int pos = atomicAdd(&cursor[d], 1);
        float w = ew[e] * iso[s] * isi[d];
        unsigned short hw = __half_as_ushort(__float2half(w));
        unsigned int pk = ((unsigned)s & 0xFFFFu) | ((unsigned)hw << 16);
        int idx = rowptr[d] + pos;
        if ((unsigned)idx < EE) pairs[idx] = pk;   // defensive: never store wild
    }
}

// ---------------- inputs fp32 -> bf16 (for layer-0 gather + res path) ----------------
__global__ __launch_bounds__(256) void k_tobf(const float* __restrict__ X,
                                              unsigned short* __restrict__ Hb) {
    int i = blockIdx.x * blockDim.x + threadIdx.x;   // NN*DD/4 threads
    if (i < NN * DD / 4) {
        float4 v = *(const float4*)&X[i * 4];
        ushort4 h;
        h.x = f2bf(v.x); h.y = f2bf(v.y); h.z = f2bf(v.z); h.w = f2bf(v.w);
        *(ushort4*)&Hb[i * 4] = h;
    }
}

// ---------------- CSR gather, bf16 src -> bf16 out, 8-deep pipelined (round-14 proven) ----------------
__global__ __launch_bounds__(256) void k_gather_bf(
        const unsigned short* __restrict__ H, const int* __restrict__ rowptr,
        const unsigned int* __restrict__ pairs, unsigned short* __restrict__ G) {
    int node = blockIdx.x * 4 + (threadIdx.x >> 6);
    if (node >= NN) return;
    int lane = threadIdx.x & 63;
    int c = lane * 2;
    int j = rowptr[node];
    int end = rowptr[node + 1];
    j = max(0, min(j, EE));
    end = max(j, min(end, EE));
    float2 a0 = make_float2(0.f, 0.f);
    float2 a1 = make_float2(0.f, 0.f);
    float2 a2 = make_float2(0.f, 0.f);
    float2 a3 = make_float2(0.f, 0.f);
    for (; j + 7 < end; j += 8) {
        unsigned p0 = pairs[j + 0];
        unsigned p1 = pairs[j + 1];
        unsigned p2 = pairs[j + 2];
        unsigned p3 = pairs[j + 3];
        unsigned p4 = pairs[j + 4];
        unsigned p5 = pairs[j + 5];
        unsigned p6 = pairs[j + 6];
        unsigned p7 = pairs[j + 7];
        int c0 = (p0 & 0xFFFFu) < NN ? (p0 & 0xFFFFu) : 0;
        int c1 = (p1 & 0xFFFFu) < NN ? (p1 & 0xFFFFu) : 0;
        int c2 = (p2 & 0xFFFFu) < NN ? (p2 & 0xFFFFu) : 0;
        int c3 = (p3 & 0xFFFFu) < NN ? (p3 & 0xFFFFu) : 0;
        int c4 = (p4 & 0xFFFFu) < NN ? (p4 & 0xFFFFu) : 0;
        int c5 = (p5 & 0xFFFFu) < NN ? (p5 & 0xFFFFu) : 0;
        int c6 = (p6 & 0xFFFFu) < NN ? (p6 & 0xFFFFu) : 0;
        int c7 = (p7 & 0xFFFFu) < NN ? (p7 & 0xFFFFu) : 0;
        ushort2 h0 = *(const ushort2*)&H[c0 * DD + c];
        ushort2 h1 = *(const ushort2*)&H[c1 * DD + c];
        ushort2 h2 = *(const ushort2*)&H[c2 * DD + c];
        ushort2 h3 = *(const ushort2*)&H[c3 * DD + c];
        ushort2 h4 = *(const ushort2*)&H[c4 * DD + c];
        ushort2 h5 = *(const ushort2*)&H[c5 * DD + c];
        ushort2 h6 = *(const ushort2*)&H[c6 * DD + c];
        ushort2 h7 = *(const ushort2*)&H[c7 * DD + c];
        float w0 = __half2float(__ushort_as_half((unsigned short)(p0 >> 16)));
        float w1 = __half2float(__ushort_as_half((unsigned short)(p1 >> 16)));
        float w2 = __half2float(__ushort_as_half((unsigned short)(p2 >> 16)));
        float w3 = __half2float(__ushort_as_half((unsigned short)(p3 >> 16)));
        float w4 = __half2float(__ushort_as_half((unsigned short)(p4 >> 16)));
        float w5 = __half2float(__ushort_as_half((unsigned short)(p5 >> 16)));
        float w6 = __half2float(__ushort_as_half((unsigned short)(p6 >> 16)));
        float w7 = __half2float(__ushort_as_half((unsigned short)(p7 >> 16)));
        a0.x = fmaf(bf2f(h0.x), w0, a0.x); a0.y = fmaf(bf2f(h0.y), w0, a0.y);
        a1.x = fmaf(bf2f(h1.x), w1, a1.x); a1.y = fmaf(bf2f(h1.y), w1, a1.y);
        a2.x = fmaf(bf2f(h2.x), w2, a2.x); a2.y = fmaf(bf2f(h2.y), w2, a2.y);
        a3.x = fmaf(bf2f(h3.x), w3, a3.x); a3.y = fmaf(bf2f(h3.y), w3, a3.y);
        a0.x = fmaf(bf2f(h4.x), w4, a0.x); a0.y = fmaf(bf2f(h4.y), w4, a0.y);
        a1.x = fmaf(bf2f(h5.x), w5, a1.x); a1.y = fmaf(bf2f(h5.y), w5, a1.y);
        a2.x = fmaf(bf2f(h6.x), w6, a2.x); a2.y = fmaf(bf2f(h6.y), w6, a2.y);
        a3.x = fmaf(bf2f(h7.x), w7, a3.x); a3.y = fmaf(bf2f(h7.y), w7, a3.y);
    }
    for (; j < end; ++j) {
        unsigned p0 = pairs[j];
        int c0 = (p0 & 0xFFFFu) < NN ? (p0 & 0xFFFFu) : 0;
        float w0 = __half2float(__ushort_as_half((unsigned short)(p0 >> 16)));
        ushort2 h0 = *(const ushort2*)&H[c0 * DD + c];
        a0.x = fmaf(bf2f(h0.x), w0, a0.x); a0.y = fmaf(bf2f(h0.y), w0, a0.y);
    }
    float ox = (a0.x + a1.x) + (a2.x + a3.x);
    float oy = (a0.y + a1.y) + (a2.y + a3.y);
    ushort2 o;
    o.x = f2bf(ox);
    o.y = f2bf(oy);
    *(ushort2*)&G[node * DD + c] = o;
}

// ---------------- W prep: fp32 [k][c] -> bf16 hi/lo, transposed layout [c][k] ----------------
__global__ __launch_bounds__(128) void k_prepw(
        const float* __restrict__ W1, const float* __restrict__ W2,
        const float* __restrict__ W3, const float* __restrict__ W4,
        const float* __restrict__ Wr,
        unsigned short* __restrict__ WH, unsigned short* __restrict__ WL) {
    int m = blockIdx.x >> 7;
    int c = blockIdx.x & 127;
    int k = threadIdx.x;
    const float* Wm = (m == 0) ? W1 : (m == 1) ? W2 : (m == 2) ? W3 : (m == 3) ? W4 : Wr;
    float x = Wm[k * 128 + c];
    unsigned short hi = f2bf(x);
    unsigned short lo = f2bf(x - bf2f(hi));
    int off = m * 16384 + c * 128 + k;
    WH[off] = hi;
    WL[off] = lo;
}

// ---------------- MFMA GEMM, bf16 input: W in registers, X-only LDS (16KB) ----------------
#define GTILE 64
__global__ __launch_bounds__(512) void k_gemm_mfma(
        const unsigned short* __restrict__ Xb,
        const unsigned short* __restrict__ Wh, const unsigned short* __restrict__ Wl,
        const float* __restrict__ bias,
        float* __restrict__ Yf, unsigned short* __restrict__ Yb, int M, int relu) {
    __shared__ unsigned short Xs[GTILE * 128];

    const int t = threadIdx.x;
    const int row0 = blockIdx.x * GTILE;

    const int lane = t & 63;
    const int wav = t >> 6;
    const int lr = lane & 15;
    const int lk = lane >> 4;

    bf16x8 bh[4], bl[4];
    {
        const int c = 16 * wav + lr;
#pragma unroll
        for (int k0 = 0; k0 < 4; ++k0) {
            int off = c * 128 + k0 * 32 + lk * 8;
            bh[k0] = *(const bf16x8*)&Wh[off];
            bl[k0] = *(const bf16x8*)&Wl[off];
        }
    }

    for (int i = t; i < GTILE * 16; i += 512) {
        int r = i >> 4;
        int c8 = i & 15;
        int gr = row0 + r;
        bf16x8 v = {0, 0, 0, 0, 0, 0, 0, 0};
        if (gr < M) v = *(const bf16x8*)&Xb[(size_t)gr * 128 + c8 * 8];
        int slot = (c8 * 8) ^ ((r & 7) << 3);
        *(bf16x8*)&Xs[r * 128 + slot] = v;
    }
    __syncthreads();

    f32x4 acc[4];
#pragma unroll
    for (int m = 0; m < 4; ++m) acc[m] = (f32x4){0.f, 0.f, 0.f, 0.f};

#pragma unroll
    for (int k0 = 0; k0 < 4; ++k0) {
        const int kbase = k0 * 32 + lk * 8;
        bf16x8 ah[4];
#pragma unroll
        for (int m = 0; m < 4; ++m) {
            int row = 16 * m + lr;
            ah[m] = *(const bf16x8*)&Xs[row * 128 + (kbase ^ ((row & 7) << 3))];
        }
#pragma unroll
        for (int m = 0; m < 4; ++m) {
            acc[m] = __builtin_amdgcn_mfma_f32_16x16x32_bf16(ah[m], bh[k0], acc[m], 0, 0, 0);
            acc[m] = __builtin_amdgcn_mfma_f32_16x16x32_bf16(ah[m], bl[k0], acc[m], 0, 0, 0);
        }
    }

    {
        int gc = 16 * wav + lr;
        float bv = bias[gc];
#pragma unroll
        for (int m = 0; m < 4; ++m) {
#pragma unroll
            for (int j = 0; j < 4; ++j) {
                int gr = row0 + 16 * m + lk * 4 + j;
                if (gr < M) {
                    float a = acc[m][j] + bv;
                    if (relu) a = fmaxf(a, 0.f);
                    if (Yb) Yb[(long long)gr * DD + gc] = f2bf(a);
                    else    Yf[(long long)gr * DD + gc] = a;
                }
            }
        }
    }
}

// ---------------- FUSED layer-3 GEMM: X0 = relu(Gb@W4 + b4 + Hin@Wr + br) ----------------
// Two bf16 input tiles in LDS (32KB), two register W-frag sets, 64 MFMAs/wave.
__global__ __launch_bounds__(512) void k_gemm_mfma_res(
        const unsigned short* __restrict__ Gb, const unsigned short* __restrict__ Hin,
        const unsigned short* __restrict__ Wh4, const unsigned short* __restrict__ Wl4,
        const unsigned short* __restrict__ Whr, const unsigned short* __restrict__ Wlr,
        const float* __restrict__ b4, const float* __restrict__ br,
        float* __restrict__ Yf, int M) {
    __shared__ unsigned short Xs[GTILE * 128];   // Gb tile
    __shared__ unsigned short Rs[GTILE * 128];   // Hin tile

    const int t = threadIdx.x;
    const int row0 = blockIdx.x * GTILE;

    const int lane = t & 63;
    const int wav = t >> 6;
    const int lr = lane & 15;
    const int lk = lane >> 4;

    bf16x8 bh4[4], bl4[4], bhr[4], blr[4];
    {
        const int c = 16 * wav + lr;
#pragma unroll
        for (int k0 = 0; k0 < 4; ++k0) {
            int off = c * 128 + k0 * 32 + lk * 8;
            bh4[k0] = *(const bf16x8*)&Wh4[off];
            bl4[k0] = *(const bf16x8*)&Wl4[off];
            bhr[k0] = *(const bf16x8*)&Whr[off];
            blr[k0] = *(const bf16x8*)&Wlr[off];
        }
    }

    for (int i = t; i < GTILE * 16; i += 512) {
        int r = i >> 4;
        int c8 = i & 15;
        int gr = row0 + r;
        bf16x8 vg = {0, 0, 0, 0, 0, 0, 0, 0};
        bf16x8 vr = {0, 0, 0, 0, 0, 0, 0, 0};
        if (gr < M) {
            vg = *(const bf16x8*)&Gb[(size_t)gr * 128 + c8 * 8];
            vr = *(const bf16x8*)&Hin[(size_t)gr * 128 + c8 * 8];
        }
        int slot = (c8 * 8) ^ ((r & 7) << 3);
        *(bf16x8*)&Xs[r * 128 + slot] = vg;
        *(bf16x8*)&Rs[r * 128 + slot] = vr;
    }
    __syncthreads();

    f32x4 accG[4], accR[4];
#pragma unroll
    for (int m = 0; m < 4; ++m) {
        accG[m] = (f32x4){0.f, 0.f, 0.f, 0.f};
        accR[m] = (f32x4){0.f, 0.f, 0.f, 0.f};
    }

#pragma unroll
    for (int k0 = 0; k0 < 4; ++k0) {
        const int kbase = k0 * 32 + lk * 8;
#pragma unroll
        for (int m = 0; m < 4; ++m) {
            int row = 16 * m + lr;
            int off = row * 128 + (kbase ^ ((row & 7) << 3));
            bf16x8 ag = *(const bf16x8*)&Xs[off];
            bf16x8 ar = *(const bf16x8*)&Rs[off];
            accG[m] = __builtin_amdgcn_mfma_f32_16x16x32_bf16(ag, bh4[k0], accG[m], 0, 0, 0);
            accG[m] = __builtin_amdgcn_mfma_f32_16x16x32_bf16(ag, bl4[k0], accG[m], 0, 0, 0);
            accR[m] = __builtin_amdgcn_mfma_f32_16x16x32_bf16(ar, bhr[k0], accR[m], 0, 0, 0);
            accR[m] = __builtin_amdgcn_mfma_f32_16x16x32_bf16(ar, blr[k0], accR[m], 0, 0, 0);
        }
    }

    {
        int gc = 16 * wav + lr;
        float bv = b4[gc] + br[gc];
#pragma unroll
        for (int m = 0; m < 4; ++m) {
#pragma unroll
            for (int j = 0; j < 4; ++j) {
                int gr = row0 + 16 * m + lk * 4 + j;
                if (gr < M) {
                    float a = accG[m][j] + accR[m][j] + bv;
                    a = fmaxf(a, 0.f);
                    Yf[(long long)gr * DD + gc] = a;
                }
            }
        }
    }
}

// ---------------- final projection: out[M,16] = X[M,128] @ Wo[128,16] + bo ----------------
__global__ __launch_bounds__(256) void k_gemm_out(
        const float* __restrict__ X, const float* __restrict__ Wo,
        const float* __restrict__ bo, float* __restrict__ Y, int M) {
    __shared__ float Wlds[128 * 16];
    int t = threadIdx.x;
    for (int i = t * 4; i < 128 * 16; i += 256 * 4) {
        *(float4*)&Wlds[i] = *(const float4*)&Wo[i];
    }
    __syncthreads();
    int r = blockIdx.x * blockDim.x + t;
    if (r < M) {
        float acc[16];
#pragma unroll
        for (int j = 0; j < 16; ++j) acc[j] = bo[j];
#pragma unroll
        for (int k = 0; k < 128; k += 4) {
            float4 x = *(const float4*)&X[(long long)r * DD + k];
#pragma unroll
            for (int j = 0; j < 16; ++j) {
                acc[j] += x.x * Wlds[(k + 0) * 16 + j] + x.y * Wlds[(k + 1) * 16 + j]
                        + x.z * Wlds[(k + 2) * 16 + j] + x.w * Wlds[(k + 3) * 16 + j];
            }
        }
#pragma unroll
        for (int j = 0; j < 16; j += 4) {
            float4 o = make_float4(acc[j], acc[j + 1], acc[j + 2], acc[j + 3]);
            *(float4*)&Y[(long long)r * CC + j] = o;
        }
    }
}

extern "C" void kernel_launch(void* const* d_in, const int* in_sizes, int n_in,
                              void* d_out, int out_size, void* d_ws, size_t ws_size,
                              hipStream_t stream) {
    const int*   src = (const int*)d_in[0];
    const int*   dst = (const int*)d_in[1];
    const float* inputs = (const float*)d_in[2];
    const float* ew  = (const float*)d_in[3];
    const float* W1  = (const float*)d_in[4];
    const float* b1  = (const float*)d_in[5];
    const float* W2  = (const float*)d_in[6];
    const float* b2  = (const float*)d_in[7];
    const float* W3  = (const float*)d_in[8];
    const float* b3  = (const float*)d_in[9];
    const float* W4  = (const float*)d_in[10];
    const float* b4  = (const float*)d_in[11];
    const float* Wr  = (const float*)d_in[12];
    const float* br  = (const float*)d_in[13];
    const float* Wo  = (const float*)d_in[14];
    const float* bo  = (const float*)d_in[15];
    float* out = (float*)d_out;

    // workspace layout
    char* p = (char*)d_ws;
    float* iso    = (float*)p; p += sizeof(float) * NN;
    float* isi    = (float*)p; p += sizeof(float) * NN;
    int*   cs     = (int*)p;   p += sizeof(int) * NN;      // reused as WHg
    int*   cd     = (int*)p;   p += sizeof(int) * NN;
    int*   cursor = (int*)p;   p += sizeof(int) * NN;
    int*   rowptr = (int*)p;   p += sizeof(int) * (NN + 1);
    int*   partial= (int*)p;   p += sizeof(int) * NBLK_SCAN;
    int*   pp     = (int*)p;   p += sizeof(int) * NBLK_SCAN;
    p = (char*)(((uintptr_t)p + 255) & ~(uintptr_t)255);
    unsigned int* pairs = (unsigned int*)p; p += sizeof(unsigned int) * EE;
    p = (char*)(((uintptr_t)p + 255) & ~(uintptr_t)255);
    float* RES    = (float*)p; p += sizeof(float) * (size_t)NN * DD;   // unused now
    float* G      = (float*)p; p += sizeof(float) * (size_t)NN * DD;
    float* X0     = (float*)p; p += sizeof(float) * (size_t)NN * DD;
    (void)RES;

    // aliases:
    unsigned short* WHg = (unsigned short*)cs;            // 160KB (cs + part of cd)
    unsigned short* WLg = WHg + 5 * 16384;                // 160KB
    unsigned int*   hist = (unsigned int*)G;              // 64 copies x 50K = 12.8MB, pre-layers
    unsigned short* Gb  = (unsigned short*)G;             // bf16 gather output (12.8MB)
    unsigned short* H   = (unsigned short*)X0;            // bf16 intermediate (lower half of X0)
    unsigned short* Hin = H + (size_t)NN * DD;            // bf16 inputs (upper half of X0)
    float* X3 = (float*)RES;                              // layer-3 fp32 output (RES region, now free)

    const int GEMM_GRID = (NN + GTILE - 1) / GTILE;       // 782
    const int NRANGES = (NN + NRANGE - 1) / NRANGE;       // 4

    // ---- degrees via LDS-privatized histogram ----
    hipMemsetAsync(cursor, 0, sizeof(int) * NN, stream);
    k_hist_lds<<<NRANGES * HCOPIES, 256, 0, stream>>>(src, dst, hist);
    k_reduce_deg<<<(NN + 255) / 256, 256, 0, stream>>>(hist, cd, iso, isi);
    k_blocksum<<<NBLK_SCAN, SBLK, 0, stream>>>(cd, partial);
    k_scanpartial<<<1, SBLK, 0, stream>>>(partial, pp, rowptr);
    k_writerowptr<<<NBLK_SCAN, SBLK, 0, stream>>>(cd, pp, rowptr);
    k_fill<<<(EE + 255) / 256, 256, 0, stream>>>(src, dst, ew, iso, isi, rowptr, cursor, pairs);

    // ---- prep bf16 weights + bf16 inputs ----
    k_prepw<<<5 * 128, 128, 0, stream>>>(W1, W2, W3, W4, Wr, WHg, WLg);
    k_tobf<<<(NN * DD / 4 + 255) / 256, 256, 0, stream>>>(inputs, Hin);

    const float* bs[3] = {b1, b2, b3};
    for (int l = 0; l < 4; ++l) {
        const unsigned short* Hs = (l == 0) ? Hin : H;
        k_gather_bf<<<(NN + 3) / 4, 256, 0, stream>>>(Hs, rowptr, pairs, Gb);

        if (l < 3) {
            k_gemm_mfma<<<GEMM_GRID, 512, 0, stream>>>(Gb, WHg + l * 16384, WLg + l * 16384,
                                                       bs[l], nullptr, H, NN, 1);
        } else {
            // fused: X3 = relu(Gb@W4 + b4 + Hin@Wr + br)
            k_gemm_mfma_res<<<GEMM_GRID, 512, 0, stream>>>(
                Gb, Hin,
                WHg + 3 * 16384, WLg + 3 * 16384,
                WHg + 4 * 16384, WLg + 4 * 16384,
                b4, br, X3, NN);
        }
    }

    k_gemm_out<<<(NN + 255) / 256, 256, 0, stream>>>(X3, Wo, bo, out, NN);
}

// Round 17
// 314.927 us; speedup vs baseline: 1.1251x; 1.0311x over previous
//
#include <hip/hip_runtime.h>
#include <hip/hip_fp16.h>

#define NN 50000
#define EE 800000
#define DD 128
#define CC 16
#define HCOPIES 64
#define NRANGE 16384   // nodes per LDS-hist range (64KB LDS)

// bucketed fill:
#define NBB 196        // dst buckets of 256 nodes (50000>>8 = 195)
#define CAPB 5120      // per-bucket capacity (avg 4082, 18+ sigma slack)
#define NCHUNK 256
#define CHUNKE ((EE + NCHUNK - 1) / NCHUNK)   // 3125

typedef __attribute__((ext_vector_type(8))) short bf16x8;
typedef __attribute__((ext_vector_type(4))) float f32x4;

__device__ inline unsigned short f2bf(float x) {
    unsigned int u = __float_as_uint(x);
    unsigned int r = (u + 0x7FFFu + ((u >> 16) & 1u)) >> 16;
    return (unsigned short)r;
}
__device__ inline float bf2f(unsigned short h) {
    return __uint_as_float(((unsigned int)h) << 16);
}

// ---------------- LDS-privatized degree histogram (packed: src lo16, dst hi16) ----------------
__global__ __launch_bounds__(256) void k_hist_lds(
        const int* __restrict__ src, const int* __restrict__ dst,
        unsigned int* __restrict__ hist) {
    __shared__ unsigned int lds[NRANGE];
    const int t = threadIdx.x;
    const int r = blockIdx.x / HCOPIES;
    const int sub = blockIdx.x % HCOPIES;
    const int base = r * NRANGE;
    const int hi = min(base + NRANGE, NN) - base;   // range size (<= NRANGE)

    for (int i = t; i < NRANGE; i += 256) lds[i] = 0;
    __syncthreads();

    const int chunk = EE / HCOPIES;                 // 12500
    const int e0 = sub * chunk;
    const int e1 = e0 + chunk;
    for (int e = e0 + t; e < e1; e += 256) {
        int s = src[e];
        int d = dst[e];
        unsigned us = (unsigned)(s - base);
        unsigned ud = (unsigned)(d - base);
        if (us < (unsigned)hi) atomicAdd(&lds[us], 1u);
        if (ud < (unsigned)hi) atomicAdd(&lds[ud], 0x10000u);
    }
    __syncthreads();

    for (int i = t; i < hi; i += 256) hist[(size_t)sub * NN + base + i] = lds[i];
}

__global__ void k_reduce_deg(const unsigned int* __restrict__ hist,
                             int* __restrict__ cd,
                             float* __restrict__ iso, float* __restrict__ isi) {
    int i = blockIdx.x * blockDim.x + threadIdx.x;
    if (i < NN) {
        unsigned int sum = 0;
#pragma unroll
        for (int c = 0; c < HCOPIES; ++c) sum += hist[(size_t)c * NN + i];
        unsigned int csv = sum & 0xFFFFu;
        unsigned int cdv = sum >> 16;
        cd[i] = (int)cdv;
        iso[i] = rsqrtf(fmaxf((float)csv, 1.0f));
        isi[i] = rsqrtf(fmaxf((float)cdv, 1.0f));
    }
}

// ---------------- hierarchical exclusive scan: cd -> rowptr ----------------
#define SBLK 256
#define NBLK_SCAN ((NN + SBLK - 1) / SBLK)   // 196

__global__ __launch_bounds__(SBLK) void k_blocksum(const int* __restrict__ cnt,
                                                   int* __restrict__ partial) {
    __shared__ int s[SBLK];
    int t = threadIdx.x;
    int i = blockIdx.x * SBLK + t;
    int v = (i < NN) ? cnt[i] : 0;
    s[t] = v;
    __syncthreads();
    for (int off = SBLK / 2; off > 0; off >>= 1) {
        if (t < off) s[t] += s[t + off];
        __syncthreads();
    }
    if (t == 0) partial[blockIdx.x] = s[0];
}

__global__ __launch_bounds__(SBLK) void k_scanpartial(const int* __restrict__ partial,
                                                      int* __restrict__ pp,
                                                      int* __restrict__ rowptr) {
    __shared__ int s[SBLK];
    int t = threadIdx.x;
    int v = (t < NBLK_SCAN) ? partial[t] : 0;
    s[t] = v;
    __syncthreads();
    for (int off = 1; off < SBLK; off <<= 1) {
        int x = (t >= off) ? s[t - off] : 0;
        __syncthreads();
        s[t] += x;
        __syncthreads();
    }
    if (t < NBLK_SCAN) pp[t] = s[t] - v;   // exclusive prefix of block partials
    if (t == SBLK - 1) rowptr[NN] = s[t];  // grand total (== EE)
}

__global__ __launch_bounds__(SBLK) void k_writerowptr(const int* __restrict__ cnt,
                                                      const int* __restrict__ pp,
                                                      int* __restrict__ rowptr) {
    __shared__ int s[SBLK];
    int t = threadIdx.x;
    int i = blockIdx.x * SBLK + t;
    int v = (i < NN) ? cnt[i] : 0;
    s[t] = v;
    __syncthreads();
    for (int off = 1; off < SBLK; off <<= 1) {
        int x = (t >= off) ? s[t - off] : 0;
        __syncthreads();
        s[t] += x;
        __syncthreads();
    }
    if (i < NN) rowptr[i] = pp[blockIdx.x] + s[t] - v;
}

// ---------------- Phase A: bin edges by dst bucket, fully-packed 8B entries ----------------
// entry.x = (src:16 | fp16 w:16)  == final pair payload; entry.y = dst & 255
__global__ __launch_bounds__(256) void k_binA(
        const int* __restrict__ src, const int* __restrict__ dst,
        const float* __restrict__ ew, const float* __restrict__ iso,
        const float* __restrict__ isi,
        int* __restrict__ gcur, uint2* __restrict__ bucketArr) {
    __shared__ unsigned int cntA[NBB];
    __shared__ unsigned int gbase[NBB];
    __shared__ unsigned int cnt2[NBB];
    const int t = threadIdx.x;
    const int e0 = blockIdx.x * CHUNKE;
    const int n = min(CHUNKE, EE - e0);

    for (int i = t; i < NBB; i += 256) { cntA[i] = 0; cnt2[i] = 0; }
    __syncthreads();

    for (int i = t; i < n; i += 256) {
        int d = dst[e0 + i];
        if ((unsigned)d < NN) atomicAdd(&cntA[d >> 8], 1u);
    }
    __syncthreads();

    for (int i = t; i < NBB; i += 256)
        gbase[i] = atomicAdd((unsigned int*)&gcur[i], cntA[i]);
    __syncthreads();

    for (int i = t; i < n; i += 256) {
        int e = e0 + i;
        int d = dst[e];
        if ((unsigned)d >= NN) continue;
        int s = src[e];
        if ((unsigned)s >= NN) continue;
        float w = ew[e] * iso[s] * isi[d];
        unsigned short hw = __half_as_ushort(__float2half(w));
        int b = d >> 8;
        unsigned pos = atomicAdd(&cnt2[b], 1u) + gbase[b];
        uint2 en;
        en.x = ((unsigned)s & 0xFFFFu) | ((unsigned)hw << 16);
        en.y = (unsigned)(d & 255);
        if (pos < CAPB) bucketArr[(size_t)b * CAPB + pos] = en;
    }
}

// ---------------- Phase B: one block per bucket -> CSR pairs (single-writer window) ----------------
__global__ __launch_bounds__(256) void k_fillB(
        const uint2* __restrict__ bucketArr, const int* __restrict__ gcur,
        const int* __restrict__ rowptr, unsigned int* __restrict__ pairs) {
    __shared__ unsigned int lcnt[256];
    __shared__ int lrp[256];
    const int t = threadIdx.x;
    const int b = blockIdx.x;
    const int node = (b << 8) + t;
    lcnt[t] = 0;
    lrp[t] = (node < NN) ? rowptr[node] : 0;
    __syncthreads();

    int cnt = min(gcur[b], CAPB);
    const uint2* seg = bucketArr + (size_t)b * CAPB;
    for (int i = t; i < cnt; i += 256) {
        uint2 en = seg[i];
        int ld = (int)(en.y & 255u);
        unsigned pos = atomicAdd(&lcnt[ld], 1u);
        int idx = lrp[ld] + (int)pos;
        if ((unsigned)idx < EE) pairs[idx] = en.x;
    }
}

// ---------------- inputs fp32 -> bf16 (for layer-0 gather + res path) ----------------
__global__ __launch_bounds__(256) void k_tobf(const float* __restrict__ X,
                                              unsigned short* __restrict__ Hb) {
    int i = blockIdx.x * blockDim.x + threadIdx.x;   // NN*DD/4 threads
    if (i < NN * DD / 4) {
        float4 v = *(const float4*)&X[i * 4];
        ushort4 h;
        h.x = f2bf(v.x); h.y = f2bf(v.y); h.z = f2bf(v.z); h.w = f2bf(v.w);
        *(ushort4*)&Hb[i * 4] = h;
    }
}

// ---------------- CSR gather, bf16 src -> bf16 out, 8-deep pipelined (proven) ----------------
__global__ __launch_bounds__(256) void k_gather_bf(
        const unsigned short* __restrict__ H, const int* __restrict__ rowptr,
        const unsigned int* __restrict__ pairs, unsigned short* __restrict__ G) {
    int node = blockIdx.x * 4 + (threadIdx.x >> 6);
    if (node >= NN) return;
    int lane = threadIdx.x & 63;
    int c = lane * 2;
    int j = rowptr[node];
    int end = rowptr[node + 1];
    j = max(0, min(j, EE));
    end = max(j, min(end, EE));
    float2 a0 = make_float2(0.f, 0.f);
    float2 a1 = make_float2(0.f, 0.f);
    float2 a2 = make_float2(0.f, 0.f);
    float2 a3 = make_float2(0.f, 0.f);
    for (; j + 7 < end; j += 8) {
        unsigned p0 = pairs[j + 0];
        unsigned p1 = pairs[j + 1];
        unsigned p2 = pairs[j + 2];
        unsigned p3 = pairs[j + 3];
        unsigned p4 = pairs[j + 4];
        unsigned p5 = pairs[j + 5];
        unsigned p6 = pairs[j + 6];
        unsigned p7 = pairs[j + 7];
        int c0 = (p0 & 0xFFFFu) < NN ? (p0 & 0xFFFFu) : 0;
        int c1 = (p1 & 0xFFFFu) < NN ? (p1 & 0xFFFFu) : 0;
        int c2 = (p2 & 0xFFFFu) < NN ? (p2 & 0xFFFFu) : 0;
        int c3 = (p3 & 0xFFFFu) < NN ? (p3 & 0xFFFFu) : 0;
        int c4 = (p4 & 0xFFFFu) < NN ? (p4 & 0xFFFFu) : 0;
        int c5 = (p5 & 0xFFFFu) < NN ? (p5 & 0xFFFFu) : 0;
        int c6 = (p6 & 0xFFFFu) < NN ? (p6 & 0xFFFFu) : 0;
        int c7 = (p7 & 0xFFFFu) < NN ? (p7 & 0xFFFFu) : 0;
        ushort2 h0 = *(const ushort2*)&H[c0 * DD + c];
        ushort2 h1 = *(const ushort2*)&H[c1 * DD + c];
        ushort2 h2 = *(const ushort2*)&H[c2 * DD + c];
        ushort2 h3 = *(const ushort2*)&H[c3 * DD + c];
        ushort2 h4 = *(const ushort2*)&H[c4 * DD + c];
        ushort2 h5 = *(const ushort2*)&H[c5 * DD + c];
        ushort2 h6 = *(const ushort2*)&H[c6 * DD + c];
        ushort2 h7 = *(const ushort2*)&H[c7 * DD + c];
        float w0 = __half2float(__ushort_as_half((unsigned short)(p0 >> 16)));
        float w1 = __half2float(__ushort_as_half((unsigned short)(p1 >> 16)));
        float w2 = __half2float(__ushort_as_half((unsigned short)(p2 >> 16)));
        float w3 = __half2float(__ushort_as_half((unsigned short)(p3 >> 16)));
        float w4 = __half2float(__ushort_as_half((unsigned short)(p4 >> 16)));
        float w5 = __half2float(__ushort_as_half((unsigned short)(p5 >> 16)));
        float w6 = __half2float(__ushort_as_half((unsigned short)(p6 >> 16)));
        float w7 = __half2float(__ushort_as_half((unsigned short)(p7 >> 16)));
        a0.x = fmaf(bf2f(h0.x), w0, a0.x); a0.y = fmaf(bf2f(h0.y), w0, a0.y);
        a1.x = fmaf(bf2f(h1.x), w1, a1.x); a1.y = fmaf(bf2f(h1.y), w1, a1.y);
        a2.x = fmaf(bf2f(h2.x), w2, a2.x); a2.y = fmaf(bf2f(h2.y), w2, a2.y);
        a3.x = fmaf(bf2f(h3.x), w3, a3.x); a3.y = fmaf(bf2f(h3.y), w3, a3.y);
        a0.x = fmaf(bf2f(h4.x), w4, a0.x); a0.y = fmaf(bf2f(h4.y), w4, a0.y);
        a1.x = fmaf(bf2f(h5.x), w5, a1.x); a1.y = fmaf(bf2f(h5.y), w5, a1.y);
        a2.x = fmaf(bf2f(h6.x), w6, a2.x); a2.y = fmaf(bf2f(h6.y), w6, a2.y);
        a3.x = fmaf(bf2f(h7.x), w7, a3.x); a3.y = fmaf(bf2f(h7.y), w7, a3.y);
    }
    for (; j < end; ++j) {
        unsigned p0 = pairs[j];
        int c0 = (p0 & 0xFFFFu) < NN ? (p0 & 0xFFFFu) : 0;
        float w0 = __half2float(__ushort_as_half((unsigned short)(p0 >> 16)));
        ushort2 h0 = *(const ushort2*)&H[c0 * DD + c];
        a0.x = fmaf(bf2f(h0.x), w0, a0.x); a0.y = fmaf(bf2f(h0.y), w0, a0.y);
    }
    float ox = (a0.x + a1.x) + (a2.x + a3.x);
    float oy = (a0.y + a1.y) + (a2.y + a3.y);
    ushort2 o;
    o.x = f2bf(ox);
    o.y = f2bf(oy);
    *(ushort2*)&G[node * DD + c] = o;
}

// ---------------- W prep: fp32 [k][c] -> bf16 hi/lo, transposed layout [c][k] ----------------
__global__ __launch_bounds__(128) void k_prepw(
        const float* __restrict__ W1, const float* __restrict__ W2,
        const float* __restrict__ W3, const float* __restrict__ W4,
        const float* __restrict__ Wr,
        unsigned short* __restrict__ WH, unsigned short* __restrict__ WL) {
    int m = blockIdx.x >> 7;
    int c = blockIdx.x & 127;
    int k = threadIdx.x;
    const float* Wm = (m == 0) ? W1 : (m == 1) ? W2 : (m == 2) ? W3 : (m == 3) ? W4 : Wr;
    float x = Wm[k * 128 + c];
    unsigned short hi = f2bf(x);
    unsigned short lo = f2bf(x - bf2f(hi));
    int off = m * 16384 + c * 128 + k;
    WH[off] = hi;
    WL[off] = lo;
}

// ---------------- MFMA GEMM, bf16 input: W in registers, X-only LDS (16KB) ----------------
#define GTILE 64
__global__ __launch_bounds__(512) void k_gemm_mfma(
        const unsigned short* __restrict__ Xb,
        const unsigned short* __restrict__ Wh, const unsigned short* __restrict__ Wl,
        const float* __restrict__ bias,
        float* __restrict__ Yf, unsigned short* __restrict__ Yb, int M, int relu) {
    __shared__ unsigned short Xs[GTILE * 128];

    const int t = threadIdx.x;
    const int row0 = blockIdx.x * GTILE;

    const int lane = t & 63;
    const int wav = t >> 6;
    const int lr = lane & 15;
    const int lk = lane >> 4;

    bf16x8 bh[4], bl[4];
    {
        const int c = 16 * wav + lr;
#pragma unroll
        for (int k0 = 0; k0 < 4; ++k0) {
            int off = c * 128 + k0 * 32 + lk * 8;
            bh[k0] = *(const bf16x8*)&Wh[off];
            bl[k0] = *(const bf16x8*)&Wl[off];
        }
    }

    for (int i = t; i < GTILE * 16; i += 512) {
        int r = i >> 4;
        int c8 = i & 15;
        int gr = row0 + r;
        bf16x8 v = {0, 0, 0, 0, 0, 0, 0, 0};
        if (gr < M) v = *(const bf16x8*)&Xb[(size_t)gr * 128 + c8 * 8];
        int slot = (c8 * 8) ^ ((r & 7) << 3);
        *(bf16x8*)&Xs[r * 128 + slot] = v;
    }
    __syncthreads();

    f32x4 acc[4];
#pragma unroll
    for (int m = 0; m < 4; ++m) acc[m] = (f32x4){0.f, 0.f, 0.f, 0.f};

#pragma unroll
    for (int k0 = 0; k0 < 4; ++k0) {
        const int kbase = k0 * 32 + lk * 8;
        bf16x8 ah[4];
#pragma unroll
        for (int m = 0; m < 4; ++m) {
            int row = 16 * m + lr;
            ah[m] = *(const bf16x8*)&Xs[row * 128 + (kbase ^ ((row & 7) << 3))];
        }
#pragma unroll
        for (int m = 0; m < 4; ++m) {
            acc[m] = __builtin_amdgcn_mfma_f32_16x16x32_bf16(ah[m], bh[k0], acc[m], 0, 0, 0);
            acc[m] = __builtin_amdgcn_mfma_f32_16x16x32_bf16(ah[m], bl[k0], acc[m], 0, 0, 0);
        }
    }

    {
        int gc = 16 * wav + lr;
        float bv = bias[gc];
#pragma unroll
        for (int m = 0; m < 4; ++m) {
#pragma unroll
            for (int j = 0; j < 4; ++j) {
                int gr = row0 + 16 * m + lk * 4 + j;
                if (gr < M) {
                    float a = acc[m][j] + bv;
                    if (relu) a = fmaxf(a, 0.f);
                    if (Yb) Yb[(long long)gr * DD + gc] = f2bf(a);
                    else    Yf[(long long)gr * DD + gc] = a;
                }
            }
        }
    }
}

// ---------------- FUSED layer-3 GEMM: X3 = relu(Gb@W4 + b4 + Hin@Wr + br) ----------------
__global__ __launch_bounds__(512) void k_gemm_mfma_res(
        const unsigned short* __restrict__ Gb, const unsigned short* __restrict__ Hin,
        const unsigned short* __restrict__ Wh4, const unsigned short* __restrict__ Wl4,
        const unsigned short* __restrict__ Whr, const unsigned short* __restrict__ Wlr,
        const float* __restrict__ b4, const float* __restrict__ br,
        float* __restrict__ Yf, int M) {
    __shared__ unsigned short Xs[GTILE * 128];   // Gb tile
    __shared__ unsigned short Rs[GTILE * 128];   // Hin tile

    const int t = threadIdx.x;
    const int row0 = blockIdx.x * GTILE;

    const int lane = t & 63;
    const int wav = t >> 6;
    const int lr = lane & 15;
    const int lk = lane >> 4;

    bf16x8 bh4[4], bl4[4], bhr[4], blr[4];
    {
        const int c = 16 * wav + lr;
#pragma unroll
        for (int k0 = 0; k0 < 4; ++k0) {
            int off = c * 128 + k0 * 32 + lk * 8;
            bh4[k0] = *(const bf16x8*)&Wh4[off];
            bl4[k0] = *(const bf16x8*)&Wl4[off];
            bhr[k0] = *(const bf16x8*)&Whr[off];
            blr[k0] = *(const bf16x8*)&Wlr[off];
        }
    }

    for (int i = t; i < GTILE * 16; i += 512) {
        int r = i >> 4;
        int c8 = i & 15;
        int gr = row0 + r;
        bf16x8 vg = {0, 0, 0, 0, 0, 0, 0, 0};
        bf16x8 vr = {0, 0, 0, 0, 0, 0, 0, 0};
        if (gr < M) {
            vg = *(const bf16x8*)&Gb[(size_t)gr * 128 + c8 * 8];
            vr = *(const bf16x8*)&Hin[(size_t)gr * 128 + c8 * 8];
        }
        int slot = (c8 * 8) ^ ((r & 7) << 3);
        *(bf16x8*)&Xs[r * 128 + slot] = vg;
        *(bf16x8*)&Rs[r * 128 + slot] = vr;
    }
    __syncthreads();

    f32x4 accG[4], accR[4];
#pragma unroll
    for (int m = 0; m < 4; ++m) {
        accG[m] = (f32x4){0.f, 0.f, 0.f, 0.f};
        accR[m] = (f32x4){0.f, 0.f, 0.f, 0.f};
    }

#pragma unroll
    for (int k0 = 0; k0 < 4; ++k0) {
        const int kbase = k0 * 32 + lk * 8;
#pragma unroll
        for (int m = 0; m < 4; ++m) {
            int row = 16 * m + lr;
            int off = row * 128 + (kbase ^ ((row & 7) << 3));
            bf16x8 ag = *(const bf16x8*)&Xs[off];
            bf16x8 ar = *(const bf16x8*)&Rs[off];
            accG[m] = __builtin_amdgcn_mfma_f32_16x16x32_bf16(ag, bh4[k0], accG[m], 0, 0, 0);
            accG[m] = __builtin_amdgcn_mfma_f32_16x16x32_bf16(ag, bl4[k0], accG[m], 0, 0, 0);
            accR[m] = __builtin_amdgcn_mfma_f32_16x16x32_bf16(ar, bhr[k0], accR[m], 0, 0, 0);
            accR[m] = __builtin_amdgcn_mfma_f32_16x16x32_bf16(ar, blr[k0], accR[m], 0, 0, 0);
        }
    }

    {
        int gc = 16 * wav + lr;
        float bv = b4[gc] + br[gc];
#pragma unroll
        for (int m = 0; m < 4; ++m) {
#pragma unroll
            for (int j = 0; j < 4; ++j) {
                int gr = row0 + 16 * m + lk * 4 + j;
                if (gr < M) {
                    float a = accG[m][j] + accR[m][j] + bv;
                    a = fmaxf(a, 0.f);
                    Yf[(long long)gr * DD + gc] = a;
                }
            }
        }
    }
}

// ---------------- final projection: out[M,16] = X[M,128] @ Wo[128,16] + bo ----------------
__global__ __launch_bounds__(256) void k_gemm_out(
        const float* __restrict__ X, const float* __restrict__ Wo,
        const float* __restrict__ bo, float* __restrict__ Y, int M) {
    __shared__ float Wlds[128 * 16];
    int t = threadIdx.x;
    for (int i = t * 4; i < 128 * 16; i += 256 * 4) {
        *(float4*)&Wlds[i] = *(const float4*)&Wo[i];
    }
    __syncthreads();
    int r = blockIdx.x * blockDim.x + t;
    if (r < M) {
        float acc[16];
#pragma unroll
        for (int j = 0; j < 16; ++j) acc[j] = bo[j];
#pragma unroll
        for (int k = 0; k < 128; k += 4) {
            float4 x = *(const float4*)&X[(long long)r * DD + k];
#pragma unroll
            for (int j = 0; j < 16; ++j) {
                acc[j] += x.x * Wlds[(k + 0) * 16 + j] + x.y * Wlds[(k + 1) * 16 + j]
                        + x.z * Wlds[(k + 2) * 16 + j] + x.w * Wlds[(k + 3) * 16 + j];
            }
        }
#pragma unroll
        for (int j = 0; j < 16; j += 4) {
            float4 o = make_float4(acc[j], acc[j + 1], acc[j + 2], acc[j + 3]);
            *(float4*)&Y[(long long)r * CC + j] = o;
        }
    }
}

extern "C" void kernel_launch(void* const* d_in, const int* in_sizes, int n_in,
                              void* d_out, int out_size, void* d_ws, size_t ws_size,
                              hipStream_t stream) {
    const int*   src = (const int*)d_in[0];
    const int*   dst = (const int*)d_in[1];
    const float* inputs = (const float*)d_in[2];
    const float* ew  = (const float*)d_in[3];
    const float* W1  = (const float*)d_in[4];
    const float* b1  = (const float*)d_in[5];
    const float* W2  = (const float*)d_in[6];
    const float* b2  = (const float*)d_in[7];
    const float* W3  = (const float*)d_in[8];
    const float* b3  = (const float*)d_in[9];
    const float* W4  = (const float*)d_in[10];
    const float* b4  = (const float*)d_in[11];
    const float* Wr  = (const float*)d_in[12];
    const float* br  = (const float*)d_in[13];
    const float* Wo  = (const float*)d_in[14];
    const float* bo  = (const float*)d_in[15];
    float* out = (float*)d_out;

    // workspace layout
    char* p = (char*)d_ws;
    float* iso    = (float*)p; p += sizeof(float) * NN;
    float* isi    = (float*)p; p += sizeof(float) * NN;
    int*   cs     = (int*)p;   p += sizeof(int) * NN;      // reused as WHg
    int*   cd     = (int*)p;   p += sizeof(int) * NN;
    int*   cursor = (int*)p;   p += sizeof(int) * NN;      // reused as bucket cursors (196)
    int*   rowptr = (int*)p;   p += sizeof(int) * (NN + 1);
    int*   partial= (int*)p;   p += sizeof(int) * NBLK_SCAN;
    int*   pp     = (int*)p;   p += sizeof(int) * NBLK_SCAN;
    p = (char*)(((uintptr_t)p + 255) & ~(uintptr_t)255);
    unsigned int* pairs = (unsigned int*)p; p += sizeof(unsigned int) * EE;
    p = (char*)(((uintptr_t)p + 255) & ~(uintptr_t)255);
    float* RES    = (float*)p; p += sizeof(float) * (size_t)NN * DD;   // reused as X3
    float* G      = (float*)p; p += sizeof(float) * (size_t)NN * DD;
    float* X0     = (float*)p; p += sizeof(float) * (size_t)NN * DD;

    // aliases:
    unsigned short* WHg = (unsigned short*)cs;            // 160KB (cs + part of cd)
    unsigned short* WLg = WHg + 5 * 16384;                // 160KB
    unsigned int*   hist = (unsigned int*)G;              // 64 copies x 50K = 12.8MB (lower G)
    uint2* bucketArr = (uint2*)((char*)G + sizeof(float) * (size_t)NN * DD / 2); // upper G, 8MB
    unsigned short* Gb  = (unsigned short*)G;             // bf16 gather output (12.8MB)
    unsigned short* H   = (unsigned short*)X0;            // bf16 intermediate (lower half of X0)
    unsigned short* Hin = H + (size_t)NN * DD;            // bf16 inputs (upper half of X0)
    float* X3 = (float*)RES;                              // layer-3 fp32 output

    const int GEMM_GRID = (NN + GTILE - 1) / GTILE;       // 782
    const int NRANGES = (NN + NRANGE - 1) / NRANGE;       // 4

    // ---- degrees via LDS-privatized histogram ----
    hipMemsetAsync(cursor, 0, sizeof(int) * NN, stream);
    k_hist_lds<<<NRANGES * HCOPIES, 256, 0, stream>>>(src, dst, hist);
    k_reduce_deg<<<(NN + 255) / 256, 256, 0, stream>>>(hist, cd, iso, isi);
    k_blocksum<<<NBLK_SCAN, SBLK, 0, stream>>>(cd, partial);
    k_scanpartial<<<1, SBLK, 0, stream>>>(partial, pp, rowptr);
    k_writerowptr<<<NBLK_SCAN, SBLK, 0, stream>>>(cd, pp, rowptr);

    // ---- bucketed CSR fill (replaces scattered-atomic k_fill) ----
    k_binA<<<NCHUNK, 256, 0, stream>>>(src, dst, ew, iso, isi, cursor, bucketArr);
    k_fillB<<<NBB, 256, 0, stream>>>(bucketArr, cursor, rowptr, pairs);

    // ---- prep bf16 weights + bf16 inputs ----
    k_prepw<<<5 * 128, 128, 0, stream>>>(W1, W2, W3, W4, Wr, WHg, WLg);
    k_tobf<<<(NN * DD / 4 + 255) / 256, 256, 0, stream>>>(inputs, Hin);

    const float* bs[3] = {b1, b2, b3};
    for (int l = 0; l < 4; ++l) {
        const unsigned short* Hs = (l == 0) ? Hin : H;
        k_gather_bf<<<(NN + 3) / 4, 256, 0, stream>>>(Hs, rowptr, pairs, Gb);

        if (l < 3) {
            k_gemm_mfma<<<GEMM_GRID, 512, 0, stream>>>(Gb, WHg + l * 16384, WLg + l * 16384,
                                                       bs[l], nullptr, H, NN, 1);
        } else {
            // fused: X3 = relu(Gb@W4 + b4 + Hin@Wr + br)
            k_gemm_mfma_res<<<GEMM_GRID, 512, 0, stream>>>(
                Gb, Hin,
                WHg + 3 * 16384, WLg + 3 * 16384,
                WHg + 4 * 16384, WLg + 4 * 16384,
                b4, br, X3, NN);
        }
    }

    k_gemm_out<<<(NN + 255) / 256, 256, 0, stream>>>(X3, Wo, bo, out, NN);
}

// Round 18
// 310.801 us; speedup vs baseline: 1.1400x; 1.0133x over previous
//
#include <hip/hip_runtime.h>
#include <hip/hip_fp16.h>

#define NN 50000
#define EE 800000
#define DD 128
#define CC 16
#define HCOPIES 64
#define NRANGE 16384   // nodes per LDS-hist range (64KB LDS)

// bucketed fill:
#define NBB 196        // dst buckets of 256 nodes (50000>>8 = 195)
#define CAPB 5120      // per-bucket capacity (avg 4082, 18+ sigma slack)
#define NCHUNK 256
#define CHUNKE ((EE + NCHUNK - 1) / NCHUNK)   // 3125

typedef __attribute__((ext_vector_type(8))) short bf16x8;
typedef __attribute__((ext_vector_type(4))) float f32x4;

__device__ inline unsigned short f2bf(float x) {
    unsigned int u = __float_as_uint(x);
    unsigned int r = (u + 0x7FFFu + ((u >> 16) & 1u)) >> 16;
    return (unsigned short)r;
}
__device__ inline float bf2f(unsigned short h) {
    return __uint_as_float(((unsigned int)h) << 16);
}

// ---------------- LDS-privatized degree histogram (packed: src lo16, dst hi16) ----------------
// Also zeroes the 196 bucket cursors (block 0) so no hipMemsetAsync is needed.
__global__ __launch_bounds__(256) void k_hist_lds(
        const int* __restrict__ src, const int* __restrict__ dst,
        unsigned int* __restrict__ hist, int* __restrict__ gcur) {
    __shared__ unsigned int lds[NRANGE];
    const int t = threadIdx.x;
    const int r = blockIdx.x / HCOPIES;
    const int sub = blockIdx.x % HCOPIES;
    const int base = r * NRANGE;
    const int hi = min(base + NRANGE, NN) - base;   // range size (<= NRANGE)

    if (blockIdx.x == 0 && t < NBB) gcur[t] = 0;    // zero bucket cursors (pre-k_binA)

    for (int i = t; i < NRANGE; i += 256) lds[i] = 0;
    __syncthreads();

    const int chunk = EE / HCOPIES;                 // 12500
    const int e0 = sub * chunk;
    const int e1 = e0 + chunk;
    for (int e = e0 + t; e < e1; e += 256) {
        int s = src[e];
        int d = dst[e];
        unsigned us = (unsigned)(s - base);
        unsigned ud = (unsigned)(d - base);
        if (us < (unsigned)hi) atomicAdd(&lds[us], 1u);
        if (ud < (unsigned)hi) atomicAdd(&lds[ud], 0x10000u);
    }
    __syncthreads();

    for (int i = t; i < hi; i += 256) hist[(size_t)sub * NN + base + i] = lds[i];
}

__global__ void k_reduce_deg(const unsigned int* __restrict__ hist,
                             int* __restrict__ cd,
                             float* __restrict__ iso, float* __restrict__ isi) {
    int i = blockIdx.x * blockDim.x + threadIdx.x;
    if (i < NN) {
        unsigned int sum = 0;
#pragma unroll
        for (int c = 0; c < HCOPIES; ++c) sum += hist[(size_t)c * NN + i];
        unsigned int csv = sum & 0xFFFFu;
        unsigned int cdv = sum >> 16;
        cd[i] = (int)cdv;
        iso[i] = rsqrtf(fmaxf((float)csv, 1.0f));
        isi[i] = rsqrtf(fmaxf((float)cdv, 1.0f));
    }
}

// ---------------- hierarchical exclusive scan: cd -> rowptr ----------------
#define SBLK 256
#define NBLK_SCAN ((NN + SBLK - 1) / SBLK)   // 196

__global__ __launch_bounds__(SBLK) void k_blocksum(const int* __restrict__ cnt,
                                                   int* __restrict__ partial) {
    __shared__ int s[SBLK];
    int t = threadIdx.x;
    int i = blockIdx.x * SBLK + t;
    int v = (i < NN) ? cnt[i] : 0;
    s[t] = v;
    __syncthreads();
    for (int off = SBLK / 2; off > 0; off >>= 1) {
        if (t < off) s[t] += s[t + off];
        __syncthreads();
    }
    if (t == 0) partial[blockIdx.x] = s[0];
}

__global__ __launch_bounds__(SBLK) void k_scanpartial(const int* __restrict__ partial,
                                                      int* __restrict__ pp,
                                                      int* __restrict__ rowptr) {
    __shared__ int s[SBLK];
    int t = threadIdx.x;
    int v = (t < NBLK_SCAN) ? partial[t] : 0;
    s[t] = v;
    __syncthreads();
    for (int off = 1; off < SBLK; off <<= 1) {
        int x = (t >= off) ? s[t - off] : 0;
        __syncthreads();
        s[t] += x;
        __syncthreads();
    }
    if (t < NBLK_SCAN) pp[t] = s[t] - v;   // exclusive prefix of block partials
    if (t == SBLK - 1) rowptr[NN] = s[t];  // grand total (== EE)
}

__global__ __launch_bounds__(SBLK) void k_writerowptr(const int* __restrict__ cnt,
                                                      const int* __restrict__ pp,
                                                      int* __restrict__ rowptr) {
    __shared__ int s[SBLK];
    int t = threadIdx.x;
    int i = blockIdx.x * SBLK + t;
    int v = (i < NN) ? cnt[i] : 0;
    s[t] = v;
    __syncthreads();
    for (int off = 1; off < SBLK; off <<= 1) {
        int x = (t >= off) ? s[t - off] : 0;
        __syncthreads();
        s[t] += x;
        __syncthreads();
    }
    if (i < NN) rowptr[i] = pp[blockIdx.x] + s[t] - v;
}

// ---------------- Phase A: bin edges by dst bucket, fully-packed 8B entries ----------------
// entry.x = (src:16 | fp16 w:16)  == final pair payload; entry.y = dst & 255
__global__ __launch_bounds__(256) void k_binA(
        const int* __restrict__ src, const int* __restrict__ dst,
        const float* __restrict__ ew, const float* __restrict__ iso,
        const float* __restrict__ isi,
        int* __restrict__ gcur, uint2* __restrict__ bucketArr) {
    __shared__ unsigned int cntA[NBB];
    __shared__ unsigned int gbase[NBB];
    __shared__ unsigned int cnt2[NBB];
    const int t = threadIdx.x;
    const int e0 = blockIdx.x * CHUNKE;
    const int n = min(CHUNKE, EE - e0);

    for (int i = t; i < NBB; i += 256) { cntA[i] = 0; cnt2[i] = 0; }
    __syncthreads();

    for (int i = t; i < n; i += 256) {
        int d = dst[e0 + i];
        if ((unsigned)d < NN) atomicAdd(&cntA[d >> 8], 1u);
    }
    __syncthreads();

    for (int i = t; i < NBB; i += 256)
        gbase[i] = atomicAdd((unsigned int*)&gcur[i], cntA[i]);
    __syncthreads();

    for (int i = t; i < n; i += 256) {
        int e = e0 + i;
        int d = dst[e];
        if ((unsigned)d >= NN) continue;
        int s = src[e];
        if ((unsigned)s >= NN) continue;
        float w = ew[e] * iso[s] * isi[d];
        unsigned short hw = __half_as_ushort(__float2half(w));
        int b = d >> 8;
        unsigned pos = atomicAdd(&cnt2[b], 1u) + gbase[b];
        uint2 en;
        en.x = ((unsigned)s & 0xFFFFu) | ((unsigned)hw << 16);
        en.y = (unsigned)(d & 255);
        if (pos < CAPB) bucketArr[(size_t)b * CAPB + pos] = en;
    }
}

// ---------------- Phase B: one block per bucket -> CSR pairs (single-writer window) ----------------
__global__ __launch_bounds__(256) void k_fillB(
        const uint2* __restrict__ bucketArr, const int* __restrict__ gcur,
        const int* __restrict__ rowptr, unsigned int* __restrict__ pairs) {
    __shared__ unsigned int lcnt[256];
    __shared__ int lrp[256];
    const int t = threadIdx.x;
    const int b = blockIdx.x;
    const int node = (b << 8) + t;
    lcnt[t] = 0;
    lrp[t] = (node < NN) ? rowptr[node] : 0;
    __syncthreads();

    int cnt = min(gcur[b], CAPB);
    const uint2* seg = bucketArr + (size_t)b * CAPB;
    for (int i = t; i < cnt; i += 256) {
        uint2 en = seg[i];
        int ld = (int)(en.y & 255u);
        unsigned pos = atomicAdd(&lcnt[ld], 1u);
        int idx = lrp[ld] + (int)pos;
        if ((unsigned)idx < EE) pairs[idx] = en.x;
    }
}

// ---------------- inputs fp32 -> bf16 (for layer-0 gather + res path) ----------------
__global__ __launch_bounds__(256) void k_tobf(const float* __restrict__ X,
                                              unsigned short* __restrict__ Hb) {
    int i = blockIdx.x * blockDim.x + threadIdx.x;   // NN*DD/4 threads
    if (i < NN * DD / 4) {
        float4 v = *(const float4*)&X[i * 4];
        ushort4 h;
        h.x = f2bf(v.x); h.y = f2bf(v.y); h.z = f2bf(v.z); h.w = f2bf(v.w);
        *(ushort4*)&Hb[i * 4] = h;
    }
}

// ---------------- CSR gather, bf16 src -> bf16 out, 8-deep pipelined (proven) ----------------
__global__ __launch_bounds__(256) void k_gather_bf(
        const unsigned short* __restrict__ H, const int* __restrict__ rowptr,
        const unsigned int* __restrict__ pairs, unsigned short* __restrict__ G) {
    int node = blockIdx.x * 4 + (threadIdx.x >> 6);
    if (node >= NN) return;
    int lane = threadIdx.x & 63;
    int c = lane * 2;
    int j = rowptr[node];
    int end = rowptr[node + 1];
    j = max(0, min(j, EE));
    end = max(j, min(end, EE));
    float2 a0 = make_float2(0.f, 0.f);
    float2 a1 = make_float2(0.f, 0.f);
    float2 a2 = make_float2(0.f, 0.f);
    float2 a3 = make_float2(0.f, 0.f);
    for (; j + 7 < end; j += 8) {
        unsigned p0 = pairs[j + 0];
        unsigned p1 = pairs[j + 1];
        unsigned p2 = pairs[j + 2];
        unsigned p3 = pairs[j + 3];
        unsigned p4 = pairs[j + 4];
        unsigned p5 = pairs[j + 5];
        unsigned p6 = pairs[j + 6];
        unsigned p7 = pairs[j + 7];
        int c0 = (p0 & 0xFFFFu) < NN ? (p0 & 0xFFFFu) : 0;
        int c1 = (p1 & 0xFFFFu) < NN ? (p1 & 0xFFFFu) : 0;
        int c2 = (p2 & 0xFFFFu) < NN ? (p2 & 0xFFFFu) : 0;
        int c3 = (p3 & 0xFFFFu) < NN ? (p3 & 0xFFFFu) : 0;
        int c4 = (p4 & 0xFFFFu) < NN ? (p4 & 0xFFFFu) : 0;
        int c5 = (p5 & 0xFFFFu) < NN ? (p5 & 0xFFFFu) : 0;
        int c6 = (p6 & 0xFFFFu) < NN ? (p6 & 0xFFFFu) : 0;
        int c7 = (p7 & 0xFFFFu) < NN ? (p7 & 0xFFFFu) : 0;
        ushort2 h0 = *(const ushort2*)&H[c0 * DD + c];
        ushort2 h1 = *(const ushort2*)&H[c1 * DD + c];
        ushort2 h2 = *(const ushort2*)&H[c2 * DD + c];
        ushort2 h3 = *(const ushort2*)&H[c3 * DD + c];
        ushort2 h4 = *(const ushort2*)&H[c4 * DD + c];
        ushort2 h5 = *(const ushort2*)&H[c5 * DD + c];
        ushort2 h6 = *(const ushort2*)&H[c6 * DD + c];
        ushort2 h7 = *(const ushort2*)&H[c7 * DD + c];
        float w0 = __half2float(__ushort_as_half((unsigned short)(p0 >> 16)));
        float w1 = __half2float(__ushort_as_half((unsigned short)(p1 >> 16)));
        float w2 = __half2float(__ushort_as_half((unsigned short)(p2 >> 16)));
        float w3 = __half2float(__ushort_as_half((unsigned short)(p3 >> 16)));
        float w4 = __half2float(__ushort_as_half((unsigned short)(p4 >> 16)));
        float w5 = __half2float(__ushort_as_half((unsigned short)(p5 >> 16)));
        float w6 = __half2float(__ushort_as_half((unsigned short)(p6 >> 16)));
        float w7 = __half2float(__ushort_as_half((unsigned short)(p7 >> 16)));
        a0.x = fmaf(bf2f(h0.x), w0, a0.x); a0.y = fmaf(bf2f(h0.y), w0, a0.y);
        a1.x = fmaf(bf2f(h1.x), w1, a1.x); a1.y = fmaf(bf2f(h1.y), w1, a1.y);
        a2.x = fmaf(bf2f(h2.x), w2, a2.x); a2.y = fmaf(bf2f(h2.y), w2, a2.y);
        a3.x = fmaf(bf2f(h3.x), w3, a3.x); a3.y = fmaf(bf2f(h3.y), w3, a3.y);
        a0.x = fmaf(bf2f(h4.x), w4, a0.x); a0.y = fmaf(bf2f(h4.y), w4, a0.y);
        a1.x = fmaf(bf2f(h5.x), w5, a1.x); a1.y = fmaf(bf2f(h5.y), w5, a1.y);
        a2.x = fmaf(bf2f(h6.x), w6, a2.x); a2.y = fmaf(bf2f(h6.y), w6, a2.y);
        a3.x = fmaf(bf2f(h7.x), w7, a3.x); a3.y = fmaf(bf2f(h7.y), w7, a3.y);
    }
    for (; j < end; ++j) {
        unsigned p0 = pairs[j];
        int c0 = (p0 & 0xFFFFu) < NN ? (p0 & 0xFFFFu) : 0;
        float w0 = __half2float(__ushort_as_half((unsigned short)(p0 >> 16)));
        ushort2 h0 = *(const ushort2*)&H[c0 * DD + c];
        a0.x = fmaf(bf2f(h0.x), w0, a0.x); a0.y = fmaf(bf2f(h0.y), w0, a0.y);
    }
    float ox = (a0.x + a1.x) + (a2.x + a3.x);
    float oy = (a0.y + a1.y) + (a2.y + a3.y);
    ushort2 o;
    o.x = f2bf(ox);
    o.y = f2bf(oy);
    *(ushort2*)&G[node * DD + c] = o;
}

// ---------------- W prep: fp32 [k][c] -> bf16 hi/lo, transposed layout [c][k] ----------------
__global__ __launch_bounds__(128) void k_prepw(
        const float* __restrict__ W1, const float* __restrict__ W2,
        const float* __restrict__ W3, const float* __restrict__ W4,
        const float* __restrict__ Wr,
        unsigned short* __restrict__ WH, unsigned short* __restrict__ WL) {
    int m = blockIdx.x >> 7;
    int c = blockIdx.x & 127;
    int k = threadIdx.x;
    const float* Wm = (m == 0) ? W1 : (m == 1) ? W2 : (m == 2) ? W3 : (m == 3) ? W4 : Wr;
    float x = Wm[k * 128 + c];
    unsigned short hi = f2bf(x);
    unsigned short lo = f2bf(x - bf2f(hi));
    int off = m * 16384 + c * 128 + k;
    WH[off] = hi;
    WL[off] = lo;
}

// ---------------- MFMA GEMM, bf16 input: W in registers, X-only LDS (16KB) ----------------
#define GTILE 64
__global__ __launch_bounds__(512) void k_gemm_mfma(
        const unsigned short* __restrict__ Xb,
        const unsigned short* __restrict__ Wh, const unsigned short* __restrict__ Wl,
        const float* __restrict__ bias,
        float* __restrict__ Yf, unsigned short* __restrict__ Yb, int M, int relu) {
    __shared__ unsigned short Xs[GTILE * 128];

    const int t = threadIdx.x;
    const int row0 = blockIdx.x * GTILE;

    const int lane = t & 63;
    const int wav = t >> 6;
    const int lr = lane & 15;
    const int lk = lane >> 4;

    bf16x8 bh[4], bl[4];
    {
        const int c = 16 * wav + lr;
#pragma unroll
        for (int k0 = 0; k0 < 4; ++k0) {
            int off = c * 128 + k0 * 32 + lk * 8;
            bh[k0] = *(const bf16x8*)&Wh[off];
            bl[k0] = *(const bf16x8*)&Wl[off];
        }
    }

    for (int i = t; i < GTILE * 16; i += 512) {
        int r = i >> 4;
        int c8 = i & 15;
        int gr = row0 + r;
        bf16x8 v = {0, 0, 0, 0, 0, 0, 0, 0};
        if (gr < M) v = *(const bf16x8*)&Xb[(size_t)gr * 128 + c8 * 8];
        int slot = (c8 * 8) ^ ((r & 7) << 3);
        *(bf16x8*)&Xs[r * 128 + slot] = v;
    }
    __syncthreads();

    f32x4 acc[4];
#pragma unroll
    for (int m = 0; m < 4; ++m) acc[m] = (f32x4){0.f, 0.f, 0.f, 0.f};

#pragma unroll
    for (int k0 = 0; k0 < 4; ++k0) {
        const int kbase = k0 * 32 + lk * 8;
        bf16x8 ah[4];
#pragma unroll
        for (int m = 0; m < 4; ++m) {
            int row = 16 * m + lr;
            ah[m] = *(const bf16x8*)&Xs[row * 128 + (kbase ^ ((row & 7) << 3))];
        }
#pragma unroll
        for (int m = 0; m < 4; ++m) {
            acc[m] = __builtin_amdgcn_mfma_f32_16x16x32_bf16(ah[m], bh[k0], acc[m], 0, 0, 0);
            acc[m] = __builtin_amdgcn_mfma_f32_16x16x32_bf16(ah[m], bl[k0], acc[m], 0, 0, 0);
        }
    }

    {
        int gc = 16 * wav + lr;
        float bv = bias[gc];
#pragma unroll
        for (int m = 0; m < 4; ++m) {
#pragma unroll
            for (int j = 0; j < 4; ++j) {
                int gr = row0 + 16 * m + lk * 4 + j;
                if (gr < M) {
                    float a = acc[m][j] + bv;
                    if (relu) a = fmaxf(a, 0.f);
                    if (Yb) Yb[(long long)gr * DD + gc] = f2bf(a);
                    else    Yf[(long long)gr * DD + gc] = a;
                }
            }
        }
    }
}

// ---------------- FUSED layer-3 GEMM: X3 = relu(Gb@W4 + b4 + Hin@Wr + br) ----------------
__global__ __launch_bounds__(512) void k_gemm_mfma_res(
        const unsigned short* __restrict__ Gb, const unsigned short* __restrict__ Hin,
        const unsigned short* __restrict__ Wh4, const unsigned short* __restrict__ Wl4,
        const unsigned short* __restrict__ Whr, const unsigned short* __restrict__ Wlr,
        const float* __restrict__ b4, const float* __restrict__ br,
        float* __restrict__ Yf, int M) {
    __shared__ unsigned short Xs[GTILE * 128];   // Gb tile
    __shared__ unsigned short Rs[GTILE * 128];   // Hin tile

    const int t = threadIdx.x;
    const int row0 = blockIdx.x * GTILE;

    const int lane = t & 63;
    const int wav = t >> 6;
    const int lr = lane & 15;
    const int lk = lane >> 4;

    bf16x8 bh4[4], bl4[4], bhr[4], blr[4];
    {
        const int c = 16 * wav + lr;
#pragma unroll
        for (int k0 = 0; k0 < 4; ++k0) {
            int off = c * 128 + k0 * 32 + lk * 8;
            bh4[k0] = *(const bf16x8*)&Wh4[off];
            bl4[k0] = *(const bf16x8*)&Wl4[off];
            bhr[k0] = *(const bf16x8*)&Whr[off];
            blr[k0] = *(const bf16x8*)&Wlr[off];
        }
    }

    for (int i = t; i < GTILE * 16; i += 512) {
        int r = i >> 4;
        int c8 = i & 15;
        int gr = row0 + r;
        bf16x8 vg = {0, 0, 0, 0, 0, 0, 0, 0};
        bf16x8 vr = {0, 0, 0, 0, 0, 0, 0, 0};
        if (gr < M) {
            vg = *(const bf16x8*)&Gb[(size_t)gr * 128 + c8 * 8];
            vr = *(const bf16x8*)&Hin[(size_t)gr * 128 + c8 * 8];
        }
        int slot = (c8 * 8) ^ ((r & 7) << 3);
        *(bf16x8*)&Xs[r * 128 + slot] = vg;
        *(bf16x8*)&Rs[r * 128 + slot] = vr;
    }
    __syncthreads();

    f32x4 accG[4], accR[4];
#pragma unroll
    for (int m = 0; m < 4; ++m) {
        accG[m] = (f32x4){0.f, 0.f, 0.f, 0.f};
        accR[m] = (f32x4){0.f, 0.f, 0.f, 0.f};
    }

#pragma unroll
    for (int k0 = 0; k0 < 4; ++k0) {
        const int kbase = k0 * 32 + lk * 8;
#pragma unroll
        for (int m = 0; m < 4; ++m) {
            int row = 16 * m + lr;
            int off = row * 128 + (kbase ^ ((row & 7) << 3));
            bf16x8 ag = *(const bf16x8*)&Xs[off];
            bf16x8 ar = *(const bf16x8*)&Rs[off];
            accG[m] = __builtin_amdgcn_mfma_f32_16x16x32_bf16(ag, bh4[k0], accG[m], 0, 0, 0);
            accG[m] = __builtin_amdgcn_mfma_f32_16x16x32_bf16(ag, bl4[k0], accG[m], 0, 0, 0);
            accR[m] = __builtin_amdgcn_mfma_f32_16x16x32_bf16(ar, bhr[k0], accR[m], 0, 0, 0);
            accR[m] = __builtin_amdgcn_mfma_f32_16x16x32_bf16(ar, blr[k0], accR[m], 0, 0, 0);
        }
    }

    {
        int gc = 16 * wav + lr;
        float bv = b4[gc] + br[gc];
#pragma unroll
        for (int m = 0; m < 4; ++m) {
#pragma unroll
            for (int j = 0; j < 4; ++j) {
                int gr = row0 + 16 * m + lk * 4 + j;
                if (gr < M) {
                    float a = accG[m][j] + accR[m][j] + bv;
                    a = fmaxf(a, 0.f);
                    Yf[(long long)gr * DD + gc] = a;
                }
            }
        }
    }
}

// ---------------- final projection: out[M,16] = X[M,128] @ Wo[128,16] + bo ----------------
__global__ __launch_bounds__(256) void k_gemm_out(
        const float* __restrict__ X, const float* __restrict__ Wo,
        const float* __restrict__ bo, float* __restrict__ Y, int M) {
    __shared__ float Wlds[128 * 16];
    int t = threadIdx.x;
    for (int i = t * 4; i < 128 * 16; i += 256 * 4) {
        *(float4*)&Wlds[i] = *(const float4*)&Wo[i];
    }
    __syncthreads();
    int r = blockIdx.x * blockDim.x + t;
    if (r < M) {
        float acc[16];
#pragma unroll
        for (int j = 0; j < 16; ++j) acc[j] = bo[j];
#pragma unroll
        for (int k = 0; k < 128; k += 4) {
            float4 x = *(const float4*)&X[(long long)r * DD + k];
#pragma unroll
            for (int j = 0; j < 16; ++j) {
                acc[j] += x.x * Wlds[(k + 0) * 16 + j] + x.y * Wlds[(k + 1) * 16 + j]
                        + x.z * Wlds[(k + 2) * 16 + j] + x.w * Wlds[(k + 3) * 16 + j];
            }
        }
#pragma unroll
        for (int j = 0; j < 16; j += 4) {
            float4 o = make_float4(acc[j], acc[j + 1], acc[j + 2], acc[j + 3]);
            *(float4*)&Y[(long long)r * CC + j] = o;
        }
    }
}

extern "C" void kernel_launch(void* const* d_in, const int* in_sizes, int n_in,
                              void* d_out, int out_size, void* d_ws, size_t ws_size,
                              hipStream_t stream) {
    const int*   src = (const int*)d_in[0];
    const int*   dst = (const int*)d_in[1];
    const float* inputs = (const float*)d_in[2];
    const float* ew  = (const float*)d_in[3];
    const float* W1  = (const float*)d_in[4];
    const float* b1  = (const float*)d_in[5];
    const float* W2  = (const float*)d_in[6];
    const float* b2  = (const float*)d_in[7];
    const float* W3  = (const float*)d_in[8];
    const float* b3  = (const float*)d_in[9];
    const float* W4  = (const float*)d_in[10];
    const float* b4  = (const float*)d_in[11];
    const float* Wr  = (const float*)d_in[12];
    const float* br  = (const float*)d_in[13];
    const float* Wo  = (const float*)d_in[14];
    const float* bo  = (const float*)d_in[15];
    float* out = (float*)d_out;

    // workspace layout
    char* p = (char*)d_ws;
    float* iso    = (float*)p; p += sizeof(float) * NN;
    float* isi    = (float*)p; p += sizeof(float) * NN;
    int*   cs     = (int*)p;   p += sizeof(int) * NN;      // reused as WHg
    int*   cd     = (int*)p;   p += sizeof(int) * NN;
    int*   cursor = (int*)p;   p += sizeof(int) * NN;      // reused as bucket cursors (196)
    int*   rowptr = (int*)p;   p += sizeof(int) * (NN + 1);
    int*   partial= (int*)p;   p += sizeof(int) * NBLK_SCAN;
    int*   pp     = (int*)p;   p += sizeof(int) * NBLK_SCAN;
    p = (char*)(((uintptr_t)p + 255) & ~(uintptr_t)255);
    unsigned int* pairs = (unsigned int*)p; p += sizeof(unsigned int) * EE;
    p = (char*)(((uintptr_t)p + 255) & ~(uintptr_t)255);
    float* RES    = (float*)p; p += sizeof(float) * (size_t)NN * DD;   // reused as X3
    float* G      = (float*)p; p += sizeof(float) * (size_t)NN * DD;
    float* X0     = (float*)p; p += sizeof(float) * (size_t)NN * DD;

    // aliases:
    unsigned short* WHg = (unsigned short*)cs;            // 160KB (cs + part of cd)
    unsigned short* WLg = WHg + 5 * 16384;                // 160KB
    unsigned int*   hist = (unsigned int*)G;              // 64 copies x 50K = 12.8MB (lower G)
    uint2* bucketArr = (uint2*)((char*)G + sizeof(float) * (size_t)NN * DD / 2); // upper G, 8MB
    unsigned short* Gb  = (unsigned short*)G;             // bf16 gather output (12.8MB)
    unsigned short* H   = (unsigned short*)X0;            // bf16 intermediate (lower half of X0)
    unsigned short* Hin = H + (size_t)NN * DD;            // bf16 inputs (upper half of X0)
    float* X3 = (float*)RES;                              // layer-3 fp32 output

    const int GEMM_GRID = (NN + GTILE - 1) / GTILE;       // 782
    const int NRANGES = (NN + NRANGE - 1) / NRANGE;       // 4

    // ---- degrees via LDS-privatized histogram (also zeroes bucket cursors) ----
    k_hist_lds<<<NRANGES * HCOPIES, 256, 0, stream>>>(src, dst, hist, cursor);
    k_reduce_deg<<<(NN + 255) / 256, 256, 0, stream>>>(hist, cd, iso, isi);
    k_blocksum<<<NBLK_SCAN, SBLK, 0, stream>>>(cd, partial);
    k_scanpartial<<<1, SBLK, 0, stream>>>(partial, pp, rowptr);
    k_writerowptr<<<NBLK_SCAN, SBLK, 0, stream>>>(cd, pp, rowptr);

    // ---- bucketed CSR fill ----
    k_binA<<<NCHUNK, 256, 0, stream>>>(src, dst, ew, iso, isi, cursor, bucketArr);
    k_fillB<<<NBB, 256, 0, stream>>>(bucketArr, cursor, rowptr, pairs);

    // ---- prep bf16 weights + bf16 inputs ----
    k_prepw<<<5 * 128, 128, 0, stream>>>(W1, W2, W3, W4, Wr, WHg, WLg);
    k_tobf<<<(NN * DD / 4 + 255) / 256, 256, 0, stream>>>(inputs, Hin);

    const float* bs[3] = {b1, b2, b3};
    for (int l = 0; l < 4; ++l) {
        const unsigned short* Hs = (l == 0) ? Hin : H;
        k_gather_bf<<<(NN + 3) / 4, 256, 0, stream>>>(Hs, rowptr, pairs, Gb);

        if (l < 3) {
            k_gemm_mfma<<<GEMM_GRID, 512, 0, stream>>>(Gb, WHg + l * 16384, WLg + l * 16384,
                                                       bs[l], nullptr, H, NN, 1);
        } else {
            // fused: X3 = relu(Gb@W4 + b4 + Hin@Wr + br)
            k_gemm_mfma_res<<<GEMM_GRID, 512, 0, stream>>>(
                Gb, Hin,
                WHg + 3 * 16384, WLg + 3 * 16384,
                WHg + 4 * 16384, WLg + 4 * 16384,
                b4, br, X3, NN);
        }
    }

    k_gemm_out<<<(NN + 255) / 256, 256, 0, stream>>>(X3, Wo, bo, out, NN);
}

// Round 19
// 306.197 us; speedup vs baseline: 1.1572x; 1.0150x over previous
//
#include <hip/hip_runtime.h>
#include <hip/hip_fp16.h>

#define NN 50000
#define EE 800000
#define DD 128
#define CC 16
#define HCOPIES 64
#define NRANGE 16384   // nodes per LDS-hist range (64KB LDS)

// bucketed fill:
#define NBB 196        // dst buckets of 256 nodes (50000>>8 = 195)
#define CAPB 5120      // per-bucket capacity (avg 4082, 18+ sigma slack)
#define NCHUNK 256
#define CHUNKE ((EE + NCHUNK - 1) / NCHUNK)   // 3125

typedef __attribute__((ext_vector_type(8))) short bf16x8;
typedef __attribute__((ext_vector_type(4))) float f32x4;

__device__ inline unsigned short f2bf(float x) {
    unsigned int u = __float_as_uint(x);
    unsigned int r = (u + 0x7FFFu + ((u >> 16) & 1u)) >> 16;
    return (unsigned short)r;
}
__device__ inline float bf2f(unsigned short h) {
    return __uint_as_float(((unsigned int)h) << 16);
}

// ---------------- LDS-privatized degree histogram (packed: src lo16, dst hi16) ----------------
// Also zeroes the 196 bucket cursors (block 0) so no hipMemsetAsync is needed.
__global__ __launch_bounds__(256) void k_hist_lds(
        const int* __restrict__ src, const int* __restrict__ dst,
        unsigned int* __restrict__ hist, int* __restrict__ gcur) {
    __shared__ unsigned int lds[NRANGE];
    const int t = threadIdx.x;
    const int r = blockIdx.x / HCOPIES;
    const int sub = blockIdx.x % HCOPIES;
    const int base = r * NRANGE;
    const int hi = min(base + NRANGE, NN) - base;   // range size (<= NRANGE)

    if (blockIdx.x == 0 && t < NBB) gcur[t] = 0;    // zero bucket cursors (pre-k_binA)

    for (int i = t; i < NRANGE; i += 256) lds[i] = 0;
    __syncthreads();

    const int chunk = EE / HCOPIES;                 // 12500
    const int e0 = sub * chunk;
    const int e1 = e0 + chunk;
    for (int e = e0 + t; e < e1; e += 256) {
        int s = src[e];
        int d = dst[e];
        unsigned us = (unsigned)(s - base);
        unsigned ud = (unsigned)(d - base);
        if (us < (unsigned)hi) atomicAdd(&lds[us], 1u);
        if (ud < (unsigned)hi) atomicAdd(&lds[ud], 0x10000u);
    }
    __syncthreads();

    for (int i = t; i < hi; i += 256) hist[(size_t)sub * NN + base + i] = lds[i];
}

// ---------------- reduce degrees + per-block partial sums (merged k_blocksum) ----------------
#define SBLK 256
#define NBLK_SCAN ((NN + SBLK - 1) / SBLK)   // 196

__global__ __launch_bounds__(SBLK) void k_reduce_deg(
        const unsigned int* __restrict__ hist,
        int* __restrict__ cd, float* __restrict__ iso, float* __restrict__ isi,
        int* __restrict__ partial) {
    __shared__ int sblk[SBLK];
    int t = threadIdx.x;
    int i = blockIdx.x * SBLK + t;
    int cdv_i = 0;
    if (i < NN) {
        unsigned int sum = 0;
#pragma unroll
        for (int c = 0; c < HCOPIES; ++c) sum += hist[(size_t)c * NN + i];
        unsigned int csv = sum & 0xFFFFu;
        unsigned int cdv = sum >> 16;
        cd[i] = (int)cdv;
        iso[i] = rsqrtf(fmaxf((float)csv, 1.0f));
        isi[i] = rsqrtf(fmaxf((float)cdv, 1.0f));
        cdv_i = (int)cdv;
    }
    sblk[t] = cdv_i;
    __syncthreads();
    for (int off = SBLK / 2; off > 0; off >>= 1) {
        if (t < off) sblk[t] += sblk[t + off];
        __syncthreads();
    }
    if (t == 0) partial[blockIdx.x] = sblk[0];
}

__global__ __launch_bounds__(SBLK) void k_scanpartial(const int* __restrict__ partial,
                                                      int* __restrict__ pp,
                                                      int* __restrict__ rowptr) {
    __shared__ int s[SBLK];
    int t = threadIdx.x;
    int v = (t < NBLK_SCAN) ? partial[t] : 0;
    s[t] = v;
    __syncthreads();
    for (int off = 1; off < SBLK; off <<= 1) {
        int x = (t >= off) ? s[t - off] : 0;
        __syncthreads();
        s[t] += x;
        __syncthreads();
    }
    if (t < NBLK_SCAN) pp[t] = s[t] - v;   // exclusive prefix of block partials
    if (t == SBLK - 1) rowptr[NN] = s[t];  // grand total (== EE)
}

__global__ __launch_bounds__(SBLK) void k_writerowptr(const int* __restrict__ cnt,
                                                      const int* __restrict__ pp,
                                                      int* __restrict__ rowptr) {
    __shared__ int s[SBLK];
    int t = threadIdx.x;
    int i = blockIdx.x * SBLK + t;
    int v = (i < NN) ? cnt[i] : 0;
    s[t] = v;
    __syncthreads();
    for (int off = 1; off < SBLK; off <<= 1) {
        int x = (t >= off) ? s[t - off] : 0;
        __syncthreads();
        s[t] += x;
        __syncthreads();
    }
    if (i < NN) rowptr[i] = pp[blockIdx.x] + s[t] - v;
}

// ---------------- Phase A: bin edges by dst bucket, fully-packed 8B entries ----------------
// entry.x = (src:16 | fp16 w:16)  == final pair payload; entry.y = dst & 255
__global__ __launch_bounds__(256) void k_binA(
        const int* __restrict__ src, const int* __restrict__ dst,
        const float* __restrict__ ew, const float* __restrict__ iso,
        const float* __restrict__ isi,
        int* __restrict__ gcur, uint2* __restrict__ bucketArr) {
    __shared__ unsigned int cntA[NBB];
    __shared__ unsigned int gbase[NBB];
    __shared__ unsigned int cnt2[NBB];
    const int t = threadIdx.x;
    const int e0 = blockIdx.x * CHUNKE;
    const int n = min(CHUNKE, EE - e0);

    for (int i = t; i < NBB; i += 256) { cntA[i] = 0; cnt2[i] = 0; }
    __syncthreads();

    for (int i = t; i < n; i += 256) {
        int d = dst[e0 + i];
        if ((unsigned)d < NN) atomicAdd(&cntA[d >> 8], 1u);
    }
    __syncthreads();

    for (int i = t; i < NBB; i += 256)
        gbase[i] = atomicAdd((unsigned int*)&gcur[i], cntA[i]);
    __syncthreads();

    for (int i = t; i < n; i += 256) {
        int e = e0 + i;
        int d = dst[e];
        if ((unsigned)d >= NN) continue;
        int s = src[e];
        if ((unsigned)s >= NN) continue;
        float w = ew[e] * iso[s] * isi[d];
        unsigned short hw = __half_as_ushort(__float2half(w));
        int b = d >> 8;
        unsigned pos = atomicAdd(&cnt2[b], 1u) + gbase[b];
        uint2 en;
        en.x = ((unsigned)s & 0xFFFFu) | ((unsigned)hw << 16);
        en.y = (unsigned)(d & 255);
        if (pos < CAPB) bucketArr[(size_t)b * CAPB + pos] = en;
    }
}

// ---------------- Phase B: one block per bucket -> CSR pairs (single-writer window) ----------------
__global__ __launch_bounds__(256) void k_fillB(
        const uint2* __restrict__ bucketArr, const int* __restrict__ gcur,
        const int* __restrict__ rowptr, unsigned int* __restrict__ pairs) {
    __shared__ unsigned int lcnt[256];
    __shared__ int lrp[256];
    const int t = threadIdx.x;
    const int b = blockIdx.x;
    const int node = (b << 8) + t;
    lcnt[t] = 0;
    lrp[t] = (node < NN) ? rowptr[node] : 0;
    __syncthreads();

    int cnt = min(gcur[b], CAPB);
    const uint2* seg = bucketArr + (size_t)b * CAPB;
    for (int i = t; i < cnt; i += 256) {
        uint2 en = seg[i];
        int ld = (int)(en.y & 255u);
        unsigned pos = atomicAdd(&lcnt[ld], 1u);
        int idx = lrp[ld] + (int)pos;
        if ((unsigned)idx < EE) pairs[idx] = en.x;
    }
}

// ---------------- merged prep: blocks [0,6250) tobf inputs; [6250,6570) split weights ----------------
#define TOBF_BLKS ((NN * DD / 4 + 255) / 256)   // 6250
__global__ __launch_bounds__(256) void k_prep(
        const float* __restrict__ X, unsigned short* __restrict__ Hb,
        const float* __restrict__ W1, const float* __restrict__ W2,
        const float* __restrict__ W3, const float* __restrict__ W4,
        const float* __restrict__ Wr,
        unsigned short* __restrict__ WH, unsigned short* __restrict__ WL) {
    const int t = threadIdx.x;
    if (blockIdx.x < TOBF_BLKS) {
        int i = blockIdx.x * 256 + t;
        if (i < NN * DD / 4) {
            float4 v = *(const float4*)&X[i * 4];
            ushort4 h;
            h.x = f2bf(v.x); h.y = f2bf(v.y); h.z = f2bf(v.z); h.w = f2bf(v.w);
            *(ushort4*)&Hb[i * 4] = h;
        }
    } else {
        // 320 blocks x 256 thr = 2 cols per block; col index cc in [0, 640)
        int cc = (blockIdx.x - TOBF_BLKS) * 2 + (t >> 7);
        int m = cc / 128;
        int c = cc & 127;
        int k = t & 127;
        const float* Wm = (m == 0) ? W1 : (m == 1) ? W2 : (m == 2) ? W3 : (m == 3) ? W4 : Wr;
        float x = Wm[k * 128 + c];
        unsigned short hi = f2bf(x);
        unsigned short lo = f2bf(x - bf2f(hi));
        int off = m * 16384 + c * 128 + k;
        WH[off] = hi;
        WL[off] = lo;
    }
}

// ---------------- CSR gather, bf16 src -> bf16 out, 8-deep pipelined (proven) ----------------
__global__ __launch_bounds__(256) void k_gather_bf(
        const unsigned short* __restrict__ H, const int* __restrict__ rowptr,
        const unsigned int* __restrict__ pairs, unsigned short* __restrict__ G) {
    int node = blockIdx.x * 4 + (threadIdx.x >> 6);
    if (node >= NN) return;
    int lane = threadIdx.x & 63;
    int c = lane * 2;
    int j = rowptr[node];
    int end = rowptr[node + 1];
    j = max(0, min(j, EE));
    end = max(j, min(end, EE));
    float2 a0 = make_float2(0.f, 0.f);
    float2 a1 = make_float2(0.f, 0.f);
    float2 a2 = make_float2(0.f, 0.f);
    float2 a3 = make_float2(0.f, 0.f);
    for (; j + 7 < end; j += 8) {
        unsigned p0 = pairs[j + 0];
        unsigned p1 = pairs[j + 1];
        unsigned p2 = pairs[j + 2];
        unsigned p3 = pairs[j + 3];
        unsigned p4 = pairs[j + 4];
        unsigned p5 = pairs[j + 5];
        unsigned p6 = pairs[j + 6];
        unsigned p7 = pairs[j + 7];
        int c0 = (p0 & 0xFFFFu) < NN ? (p0 & 0xFFFFu) : 0;
        int c1 = (p1 & 0xFFFFu) < NN ? (p1 & 0xFFFFu) : 0;
        int c2 = (p2 & 0xFFFFu) < NN ? (p2 & 0xFFFFu) : 0;
        int c3 = (p3 & 0xFFFFu) < NN ? (p3 & 0xFFFFu) : 0;
        int c4 = (p4 & 0xFFFFu) < NN ? (p4 & 0xFFFFu) : 0;
        int c5 = (p5 & 0xFFFFu) < NN ? (p5 & 0xFFFFu) : 0;
        int c6 = (p6 & 0xFFFFu) < NN ? (p6 & 0xFFFFu) : 0;
        int c7 = (p7 & 0xFFFFu) < NN ? (p7 & 0xFFFFu) : 0;
        ushort2 h0 = *(const ushort2*)&H[c0 * DD + c];
        ushort2 h1 = *(const ushort2*)&H[c1 * DD + c];
        ushort2 h2 = *(const ushort2*)&H[c2 * DD + c];
        ushort2 h3 = *(const ushort2*)&H[c3 * DD + c];
        ushort2 h4 = *(const ushort2*)&H[c4 * DD + c];
        ushort2 h5 = *(const ushort2*)&H[c5 * DD + c];
        ushort2 h6 = *(const ushort2*)&H[c6 * DD + c];
        ushort2 h7 = *(const ushort2*)&H[c7 * DD + c];
        float w0 = __half2float(__ushort_as_half((unsigned short)(p0 >> 16)));
        float w1 = __half2float(__ushort_as_half((unsigned short)(p1 >> 16)));
        float w2 = __half2float(__ushort_as_half((unsigned short)(p2 >> 16)));
        float w3 = __half2float(__ushort_as_half((unsigned short)(p3 >> 16)));
        float w4 = __half2float(__ushort_as_half((unsigned short)(p4 >> 16)));
        float w5 = __half2float(__ushort_as_half((unsigned short)(p5 >> 16)));
        float w6 = __half2float(__ushort_as_half((unsigned short)(p6 >> 16)));
        float w7 = __half2float(__ushort_as_half((unsigned short)(p7 >> 16)));
        a0.x = fmaf(bf2f(h0.x), w0, a0.x); a0.y = fmaf(bf2f(h0.y), w0, a0.y);
        a1.x = fmaf(bf2f(h1.x), w1, a1.x); a1.y = fmaf(bf2f(h1.y), w1, a1.y);
        a2.x = fmaf(bf2f(h2.x), w2, a2.x); a2.y = fmaf(bf2f(h2.y), w2, a2.y);
        a3.x = fmaf(bf2f(h3.x), w3, a3.x); a3.y = fmaf(bf2f(h3.y), w3, a3.y);
        a0.x = fmaf(bf2f(h4.x), w4, a0.x); a0.y = fmaf(bf2f(h4.y), w4, a0.y);
        a1.x = fmaf(bf2f(h5.x), w5, a1.x); a1.y = fmaf(bf2f(h5.y), w5, a1.y);
        a2.x = fmaf(bf2f(h6.x), w6, a2.x); a2.y = fmaf(bf2f(h6.y), w6, a2.y);
        a3.x = fmaf(bf2f(h7.x), w7, a3.x); a3.y = fmaf(bf2f(h7.y), w7, a3.y);
    }
    for (; j < end; ++j) {
        unsigned p0 = pairs[j];
        int c0 = (p0 & 0xFFFFu) < NN ? (p0 & 0xFFFFu) : 0;
        float w0 = __half2float(__ushort_as_half((unsigned short)(p0 >> 16)));
        ushort2 h0 = *(const ushort2*)&H[c0 * DD + c];
        a0.x = fmaf(bf2f(h0.x), w0, a0.x); a0.y = fmaf(bf2f(h0.y), w0, a0.y);
    }
    float ox = (a0.x + a1.x) + (a2.x + a3.x);
    float oy = (a0.y + a1.y) + (a2.y + a3.y);
    ushort2 o;
    o.x = f2bf(ox);
    o.y = f2bf(oy);
    *(ushort2*)&G[node * DD + c] = o;
}

// ---------------- MFMA GEMM, bf16 input: W in registers, X-only LDS (16KB) ----------------
#define GTILE 64
__global__ __launch_bounds__(512) void k_gemm_mfma(
        const unsigned short* __restrict__ Xb,
        const unsigned short* __restrict__ Wh, const unsigned short* __restrict__ Wl,
        const float* __restrict__ bias,
        float* __restrict__ Yf, unsigned short* __restrict__ Yb, int M, int relu) {
    __shared__ unsigned short Xs[GTILE * 128];

    const int t = threadIdx.x;
    const int row0 = blockIdx.x * GTILE;

    const int lane = t & 63;
    const int wav = t >> 6;
    const int lr = lane & 15;
    const int lk = lane >> 4;

    bf16x8 bh[4], bl[4];
    {
        const int c = 16 * wav + lr;
#pragma unroll
        for (int k0 = 0; k0 < 4; ++k0) {
            int off = c * 128 + k0 * 32 + lk * 8;
            bh[k0] = *(const bf16x8*)&Wh[off];
            bl[k0] = *(const bf16x8*)&Wl[off];
        }
    }

    for (int i = t; i < GTILE * 16; i += 512) {
        int r = i >> 4;
        int c8 = i & 15;
        int gr = row0 + r;
        bf16x8 v = {0, 0, 0, 0, 0, 0, 0, 0};
        if (gr < M) v = *(const bf16x8*)&Xb[(size_t)gr * 128 + c8 * 8];
        int slot = (c8 * 8) ^ ((r & 7) << 3);
        *(bf16x8*)&Xs[r * 128 + slot] = v;
    }
    __syncthreads();

    f32x4 acc[4];
#pragma unroll
    for (int m = 0; m < 4; ++m) acc[m] = (f32x4){0.f, 0.f, 0.f, 0.f};

#pragma unroll
    for (int k0 = 0; k0 < 4; ++k0) {
        const int kbase = k0 * 32 + lk * 8;
        bf16x8 ah[4];
#pragma unroll
        for (int m = 0; m < 4; ++m) {
            int row = 16 * m + lr;
            ah[m] = *(const bf16x8*)&Xs[row * 128 + (kbase ^ ((row & 7) << 3))];
        }
#pragma unroll
        for (int m = 0; m < 4; ++m) {
            acc[m] = __builtin_amdgcn_mfma_f32_16x16x32_bf16(ah[m], bh[k0], acc[m], 0, 0, 0);
            acc[m] = __builtin_amdgcn_mfma_f32_16x16x32_bf16(ah[m], bl[k0], acc[m], 0, 0, 0);
        }
    }

    {
        int gc = 16 * wav + lr;
        float bv = bias[gc];
#pragma unroll
        for (int m = 0; m < 4; ++m) {
#pragma unroll
            for (int j = 0; j < 4; ++j) {
                int gr = row0 + 16 * m + lk * 4 + j;
                if (gr < M) {
                    float a = acc[m][j] + bv;
                    if (relu) a = fmaxf(a, 0.f);
                    if (Yb) Yb[(long long)gr * DD + gc] = f2bf(a);
                    else    Yf[(long long)gr * DD + gc] = a;
                }
            }
        }
    }
}

// ---------------- FUSED layer-3 GEMM: X3 = relu(Gb@W4 + b4 + Hin@Wr + br) ----------------
__global__ __launch_bounds__(512) void k_gemm_mfma_res(
        const unsigned short* __restrict__ Gb, const unsigned short* __restrict__ Hin,
        const unsigned short* __restrict__ Wh4, const unsigned short* __restrict__ Wl4,
        const unsigned short* __restrict__ Whr, const unsigned short* __restrict__ Wlr,
        const float* __restrict__ b4, const float* __restrict__ br,
        float* __restrict__ Yf, int M) {
    __shared__ unsigned short Xs[GTILE * 128];   // Gb tile
    __shared__ unsigned short Rs[GTILE * 128];   // Hin tile

    const int t = threadIdx.x;
    const int row0 = blockIdx.x * GTILE;

    const int lane = t & 63;
    const int wav = t >> 6;
    const int lr = lane & 15;
    const int lk = lane >> 4;

    bf16x8 bh4[4], bl4[4], bhr[4], blr[4];
    {
        const int c = 16 * wav + lr;
#pragma unroll
        for (int k0 = 0; k0 < 4; ++k0) {
            int off = c * 128 + k0 * 32 + lk * 8;
            bh4[k0] = *(const bf16x8*)&Wh4[off];
            bl4[k0] = *(const bf16x8*)&Wl4[off];
            bhr[k0] = *(const bf16x8*)&Whr[off];
            blr[k0] = *(const bf16x8*)&Wlr[off];
        }
    }

    for (int i = t; i < GTILE * 16; i += 512) {
        int r = i >> 4;
        int c8 = i & 15;
        int gr = row0 + r;
        bf16x8 vg = {0, 0, 0, 0, 0, 0, 0, 0};
        bf16x8 vr = {0, 0, 0, 0, 0, 0, 0, 0};
        if (gr < M) {
            vg = *(const bf16x8*)&Gb[(size_t)gr * 128 + c8 * 8];
            vr = *(const bf16x8*)&Hin[(size_t)gr * 128 + c8 * 8];
        }
        int slot = (c8 * 8) ^ ((r & 7) << 3);
        *(bf16x8*)&Xs[r * 128 + slot] = vg;
        *(bf16x8*)&Rs[r * 128 + slot] = vr;
    }
    __syncthreads();

    f32x4 accG[4], accR[4];
#pragma unroll
    for (int m = 0; m < 4; ++m) {
        accG[m] = (f32x4){0.f, 0.f, 0.f, 0.f};
        accR[m] = (f32x4){0.f, 0.f, 0.f, 0.f};
    }

#pragma unroll
    for (int k0 = 0; k0 < 4; ++k0) {
        const int kbase = k0 * 32 + lk * 8;
#pragma unroll
        for (int m = 0; m < 4; ++m) {
            int row = 16 * m + lr;
            int off = row * 128 + (kbase ^ ((row & 7) << 3));
            bf16x8 ag = *(const bf16x8*)&Xs[off];
            bf16x8 ar = *(const bf16x8*)&Rs[off];
            accG[m] = __builtin_amdgcn_mfma_f32_16x16x32_bf16(ag, bh4[k0], accG[m], 0, 0, 0);
            accG[m] = __builtin_amdgcn_mfma_f32_16x16x32_bf16(ag, bl4[k0], accG[m], 0, 0, 0);
            accR[m] = __builtin_amdgcn_mfma_f32_16x16x32_bf16(ar, bhr[k0], accR[m], 0, 0, 0);
            accR[m] = __builtin_amdgcn_mfma_f32_16x16x32_bf16(ar, blr[k0], accR[m], 0, 0, 0);
        }
    }

    {
        int gc = 16 * wav + lr;
        float bv = b4[gc] + br[gc];
#pragma unroll
        for (int m = 0; m < 4; ++m) {
#pragma unroll
            for (int j = 0; j < 4; ++j) {
                int gr = row0 + 16 * m + lk * 4 + j;
                if (gr < M) {
                    float a = accG[m][j] + accR[m][j] + bv;
                    a = fmaxf(a, 0.f);
                    Yf[(long long)gr * DD + gc] = a;
                }
            }
        }
    }
}

// ---------------- final projection: out[M,16] = X[M,128] @ Wo[128,16] + bo ----------------
__global__ __launch_bounds__(256) void k_gemm_out(
        const float* __restrict__ X, const float* __restrict__ Wo,
        const float* __restrict__ bo, float* __restrict__ Y, int M) {
    __shared__ float Wlds[128 * 16];
    int t = threadIdx.x;
    for (int i = t * 4; i < 128 * 16; i += 256 * 4) {
        *(float4*)&Wlds[i] = *(const float4*)&Wo[i];
    }
    __syncthreads();
    int r = blockIdx.x * blockDim.x + t;
    if (r < M) {
        float acc[16];
#pragma unroll
        for (int j = 0; j < 16; ++j) acc[j] = bo[j];
#pragma unroll
        for (int k = 0; k < 128; k += 4) {
            float4 x = *(const float4*)&X[(long long)r * DD + k];
#pragma unroll
            for (int j = 0; j < 16; ++j) {
                acc[j] += x.x * Wlds[(k + 0) * 16 + j] + x.y * Wlds[(k + 1) * 16 + j]
                        + x.z * Wlds[(k + 2) * 16 + j] + x.w * Wlds[(k + 3) * 16 + j];
            }
        }
#pragma unroll
        for (int j = 0; j < 16; j += 4) {
            float4 o = make_float4(acc[j], acc[j + 1], acc[j + 2], acc[j + 3]);
            *(float4*)&Y[(long long)r * CC + j] = o;
        }
    }
}

extern "C" void kernel_launch(void* const* d_in, const int* in_sizes, int n_in,
                              void* d_out, int out_size, void* d_ws, size_t ws_size,
                              hipStream_t stream) {
    const int*   src = (const int*)d_in[0];
    const int*   dst = (const int*)d_in[1];
    const float* inputs = (const float*)d_in[2];
    const float* ew  = (const float*)d_in[3];
    const float* W1  = (const float*)d_in[4];
    const float* b1  = (const float*)d_in[5];
    const float* W2  = (const float*)d_in[6];
    const float* b2  = (const float*)d_in[7];
    const float* W3  = (const float*)d_in[8];
    const float* b3  = (const float*)d_in[9];
    const float* W4  = (const float*)d_in[10];
    const float* b4  = (const float*)d_in[11];
    const float* Wr  = (const float*)d_in[12];
    const float* br  = (const float*)d_in[13];
    const float* Wo  = (const float*)d_in[14];
    const float* bo  = (const float*)d_in[15];
    float* out = (float*)d_out;

    // workspace layout
    char* p = (char*)d_ws;
    float* iso    = (float*)p; p += sizeof(float) * NN;
    float* isi    = (float*)p; p += sizeof(float) * NN;
    int*   cs     = (int*)p;   p += sizeof(int) * NN;      // reused as WHg
    int*   cd     = (int*)p;   p += sizeof(int) * NN;
    int*   cursor = (int*)p;   p += sizeof(int) * NN;      // reused as bucket cursors (196)
    int*   rowptr = (int*)p;   p += sizeof(int) * (NN + 1);
    int*   partial= (int*)p;   p += sizeof(int) * NBLK_SCAN;
    int*   pp     = (int*)p;   p += sizeof(int) * NBLK_SCAN;
    p = (char*)(((uintptr_t)p + 255) & ~(uintptr_t)255);
    unsigned int* pairs = (unsigned int*)p; p += sizeof(unsigned int) * EE;
    p = (char*)(((uintptr_t)p + 255) & ~(uintptr_t)255);
    float* RES    = (float*)p; p += sizeof(float) * (size_t)NN * DD;   // reused as X3
    float* G      = (float*)p; p += sizeof(float) * (size_t)NN * DD;
    float* X0     = (float*)p; p += sizeof(float) * (size_t)NN * DD;

    // aliases:
    unsigned short* WHg = (unsigned short*)cs;            // 160KB (cs + part of cd)
    unsigned short* WLg = WHg + 5 * 16384;                // 160KB
    unsigned int*   hist = (unsigned int*)G;              // 64 copies x 50K = 12.8MB (lower G)
    uint2* bucketArr = (uint2*)((char*)G + sizeof(float) * (size_t)NN * DD / 2); // upper G, 8MB
    unsigned short* Gb  = (unsigned short*)G;             // bf16 gather output (12.8MB)
    unsigned short* H   = (unsigned short*)X0;            // bf16 intermediate (lower half of X0)
    unsigned short* Hin = H + (size_t)NN * DD;            // bf16 inputs (upper half of X0)
    float* X3 = (float*)RES;                              // layer-3 fp32 output

    const int GEMM_GRID = (NN + GTILE - 1) / GTILE;       // 782
    const int NRANGES = (NN + NRANGE - 1) / NRANGE;       // 4

    // ---- degrees via LDS-privatized histogram (also zeroes bucket cursors) ----
    k_hist_lds<<<NRANGES * HCOPIES, 256, 0, stream>>>(src, dst, hist, cursor);
    k_reduce_deg<<<NBLK_SCAN, SBLK, 0, stream>>>(hist, cd, iso, isi, partial);
    k_scanpartial<<<1, SBLK, 0, stream>>>(partial, pp, rowptr);
    k_writerowptr<<<NBLK_SCAN, SBLK, 0, stream>>>(cd, pp, rowptr);

    // ---- bucketed CSR fill ----
    k_binA<<<NCHUNK, 256, 0, stream>>>(src, dst, ew, iso, isi, cursor, bucketArr);
    k_fillB<<<NBB, 256, 0, stream>>>(bucketArr, cursor, rowptr, pairs);

    // ---- merged prep: bf16 inputs + split weights ----
    k_prep<<<TOBF_BLKS + 320, 256, 0, stream>>>(inputs, Hin, W1, W2, W3, W4, Wr, WHg, WLg);

    const float* bs[3] = {b1, b2, b3};
    for (int l = 0; l < 4; ++l) {
        const unsigned short* Hs = (l == 0) ? Hin : H;
        k_gather_bf<<<(NN + 3) / 4, 256, 0, stream>>>(Hs, rowptr, pairs, Gb);

        if (l < 3) {
            k_gemm_mfma<<<GEMM_GRID, 512, 0, stream>>>(Gb, WHg + l * 16384, WLg + l * 16384,
                                                       bs[l], nullptr, H, NN, 1);
        } else {
            // fused: X3 = relu(Gb@W4 + b4 + Hin@Wr + br)
            k_gemm_mfma_res<<<GEMM_GRID, 512, 0, stream>>>(
                Gb, Hin,
                WHg + 3 * 16384, WLg + 3 * 16384,
                WHg + 4 * 16384, WLg + 4 * 16384,
                b4, br, X3, NN);
        }
    }

    k_gemm_out<<<(NN + 255) / 256, 256, 0, stream>>>(X3, Wo, bo, out, NN);
}